// Round 1
// baseline (2027.622 us; speedup 1.0000x reference)
//
#include <hip/hip_runtime.h>
#include <hip/hip_bf16.h>
#include <math.h>

typedef __bf16 bf16x8_t __attribute__((ext_vector_type(8)));
typedef float f32x4 __attribute__((ext_vector_type(4)));
typedef unsigned short ushort8 __attribute__((ext_vector_type(8)));
typedef unsigned short ushort4_t __attribute__((ext_vector_type(4)));

__device__ inline unsigned short f2bf(float f) {
  unsigned int u = __builtin_bit_cast(unsigned int, f);
  u += 0x7fffu + ((u >> 16) & 1u);
  return (unsigned short)(u >> 16);
}
__device__ inline float b2f(unsigned short s) {
  unsigned int u = ((unsigned int)s) << 16;
  return __builtin_bit_cast(float, u);
}

#define BM 64
#define BN 64
#define BKK 32
#define LDT (BKK + 8) /* 40 ushorts: keeps 16B alignment for 8-elem reads */

// C[M,N] = A[M,K] @ Bw[K,N]; A fp32 or bf16, Bw fp32 (converted on stage), C fp32 or bf16
template <bool A_BF16, bool OUT_BF16>
__global__ __launch_bounds__(256) void gemm_k(const void* __restrict__ Av,
                                              const float* __restrict__ Bw,
                                              void* __restrict__ Cv,
                                              int M, int N, int K) {
  __shared__ __align__(16) unsigned short As[BM][LDT];
  __shared__ __align__(16) unsigned short Bs[BN][LDT];  // transposed: Bs[n][k]
  const int t = threadIdx.x;
  const int lane = t & 63;
  const int wave = t >> 6;
  const int wr = wave >> 1, wc = wave & 1;
  const int la = lane & 15;  // frag row(A)/col(B,D)
  const int lk = lane >> 4;  // k-group
  const int bm = blockIdx.y * BM, bn = blockIdx.x * BN;

  const int ar = t >> 2, ak = (t & 3) * 8;
  const int bk = t >> 3, bn8 = (t & 7) * 8;

  f32x4 acc[2][2] = {};

  for (int k0 = 0; k0 < K; k0 += BKK) {
    // stage A tile (BM x BKK)
    if (A_BF16) {
      const unsigned short* A = (const unsigned short*)Av;
      ushort8 v = *(const ushort8*)(A + (size_t)(bm + ar) * K + (k0 + ak));
      *(ushort8*)&As[ar][ak] = v;
    } else {
      const float* A = (const float*)Av;
      const float* p = A + (size_t)(bm + ar) * K + (k0 + ak);
      float4 v0 = *(const float4*)p;
      float4 v1 = *(const float4*)(p + 4);
      ushort8 v;
      v[0] = f2bf(v0.x); v[1] = f2bf(v0.y); v[2] = f2bf(v0.z); v[3] = f2bf(v0.w);
      v[4] = f2bf(v1.x); v[5] = f2bf(v1.y); v[6] = f2bf(v1.z); v[7] = f2bf(v1.w);
      *(ushort8*)&As[ar][ak] = v;
    }
    // stage B tile transposed (Bs[n][k] = Bw[k0+k][bn+n])
    {
      const float* p = Bw + (size_t)(k0 + bk) * N + (bn + bn8);
      float4 v0 = *(const float4*)p;
      float4 v1 = *(const float4*)(p + 4);
      float vv[8] = {v0.x, v0.y, v0.z, v0.w, v1.x, v1.y, v1.z, v1.w};
#pragma unroll
      for (int j = 0; j < 8; ++j) Bs[bn8 + j][bk] = f2bf(vv[j]);
    }
    __syncthreads();

    bf16x8_t a[2], bb[2];
#pragma unroll
    for (int m = 0; m < 2; ++m)
      a[m] = __builtin_bit_cast(bf16x8_t, *(const ushort8*)&As[wr * 32 + m * 16 + la][lk * 8]);
#pragma unroll
    for (int n = 0; n < 2; ++n)
      bb[n] = __builtin_bit_cast(bf16x8_t, *(const ushort8*)&Bs[wc * 32 + n * 16 + la][lk * 8]);
#pragma unroll
    for (int m = 0; m < 2; ++m)
#pragma unroll
      for (int n = 0; n < 2; ++n)
        acc[m][n] = __builtin_amdgcn_mfma_f32_16x16x32_bf16(a[m], bb[n], acc[m][n], 0, 0, 0);
    __syncthreads();
  }

// epilogue: D col=lane&15, row=(lane>>4)*4+reg
#pragma unroll
  for (int m = 0; m < 2; ++m) {
#pragma unroll
    for (int n = 0; n < 2; ++n) {
#pragma unroll
      for (int r = 0; r < 4; ++r) {
        int row = bm + wr * 32 + m * 16 + lk * 4 + r;
        int col = bn + wc * 32 + n * 16 + la;
        float v = acc[m][n][r];
        if (OUT_BF16)
          ((unsigned short*)Cv)[(size_t)row * N + col] = f2bf(v);
        else
          ((float*)Cv)[(size_t)row * N + col] = v;
      }
    }
  }
}

// in-place RoPE on bf16 matrix with row length `rowlen`, pairs (2i,2i+1) within each 128-wide head
__global__ void rope_k(unsigned short* X, const float* __restrict__ cs,
                       const float* __restrict__ sn, int log2ppr, int rowlen, int total) {
  int idx = blockIdx.x * blockDim.x + threadIdx.x;
  if (idx >= total) return;
  int row = idx >> log2ppr;                 // b*S + s
  int p = idx & ((1 << log2ppr) - 1);       // pair index within row
  int h = p >> 6, i = p & 63;
  int s = row & 2047;                       // row % S (S=2048)
  float c = cs[s * 64 + i], sv = sn[s * 64 + i];
  unsigned short* base = X + (size_t)row * rowlen + h * 128 + 2 * i;
  float e = b2f(base[0]), o = b2f(base[1]);
  base[0] = f2bf(e * c - o * sv);
  base[1] = f2bf(e * sv + o * c);
}

// causal GQA flash attention, fp32 vector math.
// grid: (S/32, 16 heads, B). block: 256 threads. QB=32, KB=64.
__global__ __launch_bounds__(256) void attn_k(const unsigned short* __restrict__ Qb,
                                              const unsigned short* __restrict__ Kb,
                                              const unsigned short* __restrict__ Vb,
                                              unsigned short* __restrict__ Ob) {
  const int S = 2048, DQ = 2048, DKV = 512;
  __shared__ __align__(16) float Qs[32][132];
  __shared__ __align__(16) unsigned short Ks[64][136];
  __shared__ __align__(16) unsigned short Vs[64][136];
  __shared__ float Ss[32][68];

  const int t = threadIdx.x;
  const int b = blockIdx.z, h = blockIdx.y;
  const int q0 = blockIdx.x * 32;
  const int g = h >> 2;  // kv group = h / N_REP
  const int r = t >> 3;  // q row 0..31
  const int c8 = t & 7;  // col phase (QK) / d-slice (PV)

  // stage Q tile, scale baked in
  {
    const float scale = 0.08838834764831845f;  // 1/sqrt(128)
    const unsigned short* qp = Qb + (size_t)(b * S + q0 + r) * DQ + h * 128 + c8 * 16;
    ushort8 v0 = *(const ushort8*)qp;
    ushort8 v1 = *(const ushort8*)(qp + 8);
#pragma unroll
    for (int j = 0; j < 8; ++j) {
      Qs[r][c8 * 16 + j] = b2f(v0[j]) * scale;
      Qs[r][c8 * 16 + 8 + j] = b2f(v1[j]) * scale;
    }
  }

  float o[16];
#pragma unroll
  for (int d = 0; d < 16; ++d) o[d] = 0.f;
  float m_r = -1e30f, l_r = 0.f;

  const int n_kt = q0 / 64 + 1;
  const int kr = t >> 2, kd = (t & 3) * 32;

  for (int kt = 0; kt < n_kt; ++kt) {
    const int k0 = kt * 64;
    __syncthreads();  // prev PV done (also covers Q staging at kt=0)
    {
      const unsigned short* kp = Kb + (size_t)(b * S + k0 + kr) * DKV + g * 128 + kd;
      const unsigned short* vp = Vb + (size_t)(b * S + k0 + kr) * DKV + g * 128 + kd;
#pragma unroll
      for (int u = 0; u < 4; ++u) {
        *(ushort8*)&Ks[kr][kd + u * 8] = *(const ushort8*)(kp + u * 8);
        *(ushort8*)&Vs[kr][kd + u * 8] = *(const ushort8*)(vp + u * 8);
      }
    }
    __syncthreads();

    // scores: thread handles row r, cols c8+8j
    float s[8];
#pragma unroll
    for (int j = 0; j < 8; ++j) s[j] = 0.f;
    for (int d4 = 0; d4 < 128; d4 += 4) {
      float qa = Qs[r][d4], qb = Qs[r][d4 + 1], qc = Qs[r][d4 + 2], qd = Qs[r][d4 + 3];
#pragma unroll
      for (int j = 0; j < 8; ++j) {
        int c = c8 + 8 * j;
        ushort4_t kv = *(const ushort4_t*)&Ks[c][d4];
        s[j] += qa * b2f(kv[0]) + qb * b2f(kv[1]) + qc * b2f(kv[2]) + qd * b2f(kv[3]);
      }
    }
    if (kt == n_kt - 1) {
#pragma unroll
      for (int j = 0; j < 8; ++j) {
        int kg = k0 + c8 + 8 * j;
        if (kg > q0 + r) s[j] = -1e30f;
      }
    }
    // online softmax (8 threads per row are consecutive lanes)
    float tm = s[0];
#pragma unroll
    for (int j = 1; j < 8; ++j) tm = fmaxf(tm, s[j]);
#pragma unroll
    for (int off = 1; off < 8; off <<= 1) tm = fmaxf(tm, __shfl_xor(tm, off, 8));
    float m_new = fmaxf(m_r, tm);
    float sc = __expf(m_r - m_new);
    float ts = 0.f;
#pragma unroll
    for (int j = 0; j < 8; ++j) {
      float p = __expf(s[j] - m_new);
      ts += p;
      Ss[r][c8 + 8 * j] = p;
    }
#pragma unroll
    for (int off = 1; off < 8; off <<= 1) ts += __shfl_xor(ts, off, 8);
    l_r = l_r * sc + ts;
    m_r = m_new;
#pragma unroll
    for (int d = 0; d < 16; ++d) o[d] *= sc;
    __syncthreads();  // Ss visible to all

    // PV: thread handles row r, d-slice c8*16..+16
    for (int c = 0; c < 64; ++c) {
      float p = Ss[r][c];
      ushort8 v0 = *(const ushort8*)&Vs[c][c8 * 16];
      ushort8 v1 = *(const ushort8*)&Vs[c][c8 * 16 + 8];
#pragma unroll
      for (int d = 0; d < 8; ++d) {
        o[d] += p * b2f(v0[d]);
        o[8 + d] += p * b2f(v1[d]);
      }
    }
  }

  float inv = 1.f / l_r;
  unsigned short* op = Ob + (size_t)(b * S + q0 + r) * DQ + h * 128 + c8 * 16;
  ushort8 w0, w1;
#pragma unroll
  for (int d = 0; d < 8; ++d) {
    w0[d] = f2bf(o[d] * inv);
    w1[d] = f2bf(o[8 + d] * inv);
  }
  *(ushort8*)op = w0;
  *(ushort8*)(op + 8) = w1;
}

extern "C" void kernel_launch(void* const* d_in, const int* in_sizes, int n_in,
                              void* d_out, int out_size, void* d_ws, size_t ws_size,
                              hipStream_t stream) {
  const float* x = (const float*)d_in[0];
  const float* rc = (const float*)d_in[1];
  const float* rs = (const float*)d_in[2];
  const float* Wq = (const float*)d_in[3];
  const float* Wk = (const float*)d_in[4];
  const float* Wv = (const float*)d_in[5];
  const float* Wo = (const float*)d_in[6];
  float* out = (float*)d_out;

  const int B = 2, S = 2048, DM = 2048, DKV = 512;
  const int M = B * S;  // 4096

  unsigned short* Qb = (unsigned short*)d_ws;              // M x 2048 bf16
  unsigned short* Kb = Qb + (size_t)M * DM;                // M x 512
  unsigned short* Vb = Kb + (size_t)M * DKV;               // M x 512
  unsigned short* Ob = Vb + (size_t)M * DKV;               // M x 2048

  dim3 blk(256);
  gemm_k<false, true><<<dim3(DM / 64, M / 64), blk, 0, stream>>>(x, Wq, Qb, M, DM, DM);
  gemm_k<false, true><<<dim3(DKV / 64, M / 64), blk, 0, stream>>>(x, Wk, Kb, M, DKV, DM);
  gemm_k<false, true><<<dim3(DKV / 64, M / 64), blk, 0, stream>>>(x, Wv, Vb, M, DKV, DM);

  int totq = M * (DM / 2);
  rope_k<<<(totq + 255) / 256, blk, 0, stream>>>(Qb, rc, rs, 10, DM, totq);
  int totk = M * (DKV / 2);
  rope_k<<<(totk + 255) / 256, blk, 0, stream>>>(Kb, rc, rs, 8, DKV, totk);

  attn_k<<<dim3(S / 32, 16, B), blk, 0, stream>>>(Qb, Kb, Vb, Ob);

  gemm_k<true, false><<<dim3(DM / 64, M / 64), blk, 0, stream>>>(Ob, Wo, out, M, DM, DM);
}

// Round 2
// 741.131 us; speedup vs baseline: 2.7358x; 2.7358x over previous
//
#include <hip/hip_runtime.h>
#include <hip/hip_bf16.h>
#include <math.h>

typedef __bf16 bf16x8_t __attribute__((ext_vector_type(8)));
typedef float f32x4 __attribute__((ext_vector_type(4)));
typedef unsigned short ushort8 __attribute__((ext_vector_type(8)));

__device__ inline unsigned short f2bf(float f) {
  unsigned int u = __builtin_bit_cast(unsigned int, f);
  u += 0x7fffu + ((u >> 16) & 1u);
  return (unsigned short)(u >> 16);
}
__device__ inline float b2f(unsigned short s) {
  unsigned int u = ((unsigned int)s) << 16;
  return __builtin_bit_cast(float, u);
}

#define BM 64
#define BN 64
#define BKK 32
#define LDT (BKK + 8)

// C[M,N] = A[M,K] @ Bw[K,N]; A fp32 or bf16, Bw fp32 (converted on stage), C fp32 or bf16
template <bool A_BF16, bool OUT_BF16>
__global__ __launch_bounds__(256) void gemm_k(const void* __restrict__ Av,
                                              const float* __restrict__ Bw,
                                              void* __restrict__ Cv,
                                              int M, int N, int K) {
  __shared__ __align__(16) unsigned short As[BM][LDT];
  __shared__ __align__(16) unsigned short Bs[BN][LDT];
  const int t = threadIdx.x;
  const int lane = t & 63;
  const int wave = t >> 6;
  const int wr = wave >> 1, wc = wave & 1;
  const int la = lane & 15;
  const int lk = lane >> 4;
  const int bm = blockIdx.y * BM, bn = blockIdx.x * BN;

  const int ar = t >> 2, ak = (t & 3) * 8;
  const int bk = t >> 3, bn8 = (t & 7) * 8;

  f32x4 acc[2][2] = {};

  for (int k0 = 0; k0 < K; k0 += BKK) {
    if (A_BF16) {
      const unsigned short* A = (const unsigned short*)Av;
      ushort8 v = *(const ushort8*)(A + (size_t)(bm + ar) * K + (k0 + ak));
      *(ushort8*)&As[ar][ak] = v;
    } else {
      const float* A = (const float*)Av;
      const float* p = A + (size_t)(bm + ar) * K + (k0 + ak);
      float4 v0 = *(const float4*)p;
      float4 v1 = *(const float4*)(p + 4);
      ushort8 v;
      v[0] = f2bf(v0.x); v[1] = f2bf(v0.y); v[2] = f2bf(v0.z); v[3] = f2bf(v0.w);
      v[4] = f2bf(v1.x); v[5] = f2bf(v1.y); v[6] = f2bf(v1.z); v[7] = f2bf(v1.w);
      *(ushort8*)&As[ar][ak] = v;
    }
    {
      const float* p = Bw + (size_t)(k0 + bk) * N + (bn + bn8);
      float4 v0 = *(const float4*)p;
      float4 v1 = *(const float4*)(p + 4);
      float vv[8] = {v0.x, v0.y, v0.z, v0.w, v1.x, v1.y, v1.z, v1.w};
#pragma unroll
      for (int j = 0; j < 8; ++j) Bs[bn8 + j][bk] = f2bf(vv[j]);
    }
    __syncthreads();

    bf16x8_t a[2], bb[2];
#pragma unroll
    for (int m = 0; m < 2; ++m)
      a[m] = __builtin_bit_cast(bf16x8_t, *(const ushort8*)&As[wr * 32 + m * 16 + la][lk * 8]);
#pragma unroll
    for (int n = 0; n < 2; ++n)
      bb[n] = __builtin_bit_cast(bf16x8_t, *(const ushort8*)&Bs[wc * 32 + n * 16 + la][lk * 8]);
#pragma unroll
    for (int m = 0; m < 2; ++m)
#pragma unroll
      for (int n = 0; n < 2; ++n)
        acc[m][n] = __builtin_amdgcn_mfma_f32_16x16x32_bf16(a[m], bb[n], acc[m][n], 0, 0, 0);
    __syncthreads();
  }

#pragma unroll
  for (int m = 0; m < 2; ++m) {
#pragma unroll
    for (int n = 0; n < 2; ++n) {
#pragma unroll
      for (int r = 0; r < 4; ++r) {
        int row = bm + wr * 32 + m * 16 + lk * 4 + r;
        int col = bn + wc * 32 + n * 16 + la;
        float v = acc[m][n][r];
        if (OUT_BF16)
          ((unsigned short*)Cv)[(size_t)row * N + col] = f2bf(v);
        else
          ((float*)Cv)[(size_t)row * N + col] = v;
      }
    }
  }
}

__global__ void rope_k(unsigned short* X, const float* __restrict__ cs,
                       const float* __restrict__ sn, int log2ppr, int rowlen, int total) {
  int idx = blockIdx.x * blockDim.x + threadIdx.x;
  if (idx >= total) return;
  int row = idx >> log2ppr;
  int p = idx & ((1 << log2ppr) - 1);
  int h = p >> 6, i = p & 63;
  int s = row & 2047;
  float c = cs[s * 64 + i], sv = sn[s * 64 + i];
  unsigned short* base = X + (size_t)row * rowlen + h * 128 + 2 * i;
  float e = b2f(base[0]), o = b2f(base[1]);
  base[0] = f2bf(e * c - o * sv);
  base[1] = f2bf(e * sv + o * c);
}

// Vt[(b*4+g)*128 + d][s] = V[(b*2048+s)*512 + g*128 + d]
__global__ void transpose_v(const unsigned short* __restrict__ V, unsigned short* __restrict__ Vt) {
  __shared__ unsigned short tile[32][33];
  int bg = blockIdx.z;
  int b = bg >> 2, g = bg & 3;
  int s0 = blockIdx.x * 32, d0 = blockIdx.y * 32;
  int tx = threadIdx.x, ty = threadIdx.y;  // 32 x 8
#pragma unroll
  for (int i = 0; i < 32; i += 8)
    tile[ty + i][tx] = V[((size_t)(b * 2048 + s0 + ty + i)) * 512 + g * 128 + d0 + tx];
  __syncthreads();
#pragma unroll
  for (int i = 0; i < 32; i += 8)
    Vt[((size_t)(bg * 128 + d0 + ty + i)) * 2048 + s0 + tx] = tile[tx][ty + i];
}

// MFMA flash attention. grid (S/128, 16 heads, B), block 256 (4 waves x 32 q-rows).
__global__ __launch_bounds__(256) void attn_mfma(const unsigned short* __restrict__ Qb,
                                                 const unsigned short* __restrict__ Kb,
                                                 const unsigned short* __restrict__ Vt,
                                                 unsigned short* __restrict__ Ob) {
  const int S = 2048;
  __shared__ __align__(16) unsigned short KsA[64 * 128];   // swizzled [row][d]
  __shared__ __align__(16) unsigned short VsA[128 * 64];   // swizzled [d][kv]
  __shared__ __align__(16) unsigned short PsA[4 * 32 * 64]; // per-wave P
  char* Ksb = (char*)KsA;
  char* Vsb = (char*)VsA;

  const int t = threadIdx.x;
  const int w = t >> 6, lane = t & 63;
  const int la = lane & 15, lk = lane >> 4;
  const int b = blockIdx.z, h = blockIdx.y, g = h >> 2;
  const int q0 = blockIdx.x * 128;
  const int qw = q0 + w * 32;
  const float scale = 0.08838834764831845f;  // 1/sqrt(128)

  // Q fragments in registers: qf[qi][dt], A-frag row = la, k elems = dt*32 + lk*8 + i
  bf16x8_t qf[2][4];
#pragma unroll
  for (int qi = 0; qi < 2; ++qi)
#pragma unroll
    for (int dt = 0; dt < 4; ++dt)
      qf[qi][dt] = __builtin_bit_cast(
          bf16x8_t, *(const ushort8*)(Qb + (size_t)(b * S + qw + qi * 16 + la) * 2048 + h * 128 +
                                      dt * 32 + lk * 8));

  f32x4 oa[2][8];
#pragma unroll
  for (int qi = 0; qi < 2; ++qi)
#pragma unroll
    for (int dt = 0; dt < 8; ++dt) oa[qi][dt] = (f32x4){0.f, 0.f, 0.f, 0.f};
  float mr[2][4], lr[2][4];
#pragma unroll
  for (int qi = 0; qi < 2; ++qi)
#pragma unroll
    for (int r = 0; r < 4; ++r) {
      mr[qi][r] = -1e30f;
      lr[qi][r] = 0.f;
    }

  const int n_kt = 2 * blockIdx.x + 2;
  const int krow = t >> 2, kc0 = (t & 3) * 4;
  const int vrow = t >> 1, vc0 = (t & 1) * 4;
  char* pw = (char*)PsA + w * 4096;

  for (int kt = 0; kt < n_kt; ++kt) {
    const int k0 = kt * 64;
    __syncthreads();  // all waves done with previous K/V tiles
    {
      const unsigned short* ksrc = Kb + (size_t)(b * S + k0 + krow) * 512 + g * 128;
#pragma unroll
      for (int u = 0; u < 4; ++u) {
        int c = kc0 + u;
        *(ushort8*)(Ksb + krow * 256 + (((c ^ (krow & 7))) << 4)) = *(const ushort8*)(ksrc + c * 8);
      }
      const unsigned short* vsrc = Vt + (size_t)((b * 4 + g) * 128 + vrow) * 2048 + k0;
#pragma unroll
      for (int u = 0; u < 4; ++u) {
        int c = vc0 + u;
        *(ushort8*)(Vsb + vrow * 128 + (((c ^ (vrow & 7))) << 4)) = *(const ushort8*)(vsrc + c * 8);
      }
    }
    __syncthreads();

    if (k0 > qw + 31) continue;  // this wave fully masked for this tile (barriers already done)

    // QK^T: sacc[qi][ktc], rows q (C-layout), cols k
    f32x4 sacc[2][4];
#pragma unroll
    for (int qi = 0; qi < 2; ++qi)
#pragma unroll
      for (int ktc = 0; ktc < 4; ++ktc) sacc[qi][ktc] = (f32x4){0.f, 0.f, 0.f, 0.f};
#pragma unroll
    for (int ktc = 0; ktc < 4; ++ktc) {
      int row = ktc * 16 + la;
#pragma unroll
      for (int dt = 0; dt < 4; ++dt) {
        bf16x8_t kf = __builtin_bit_cast(
            bf16x8_t, *(const ushort8*)(Ksb + row * 256 + ((((dt << 2) + lk) ^ (row & 7)) << 4)));
        sacc[0][ktc] = __builtin_amdgcn_mfma_f32_16x16x32_bf16(qf[0][dt], kf, sacc[0][ktc], 0, 0, 0);
        sacc[1][ktc] = __builtin_amdgcn_mfma_f32_16x16x32_bf16(qf[1][dt], kf, sacc[1][ktc], 0, 0, 0);
      }
    }

    const bool domask = (kt >= n_kt - 2);
#pragma unroll
    for (int qi = 0; qi < 2; ++qi) {
      float p[4][4], tm[4];
#pragma unroll
      for (int r = 0; r < 4; ++r) tm[r] = -1e30f;
#pragma unroll
      for (int ktc = 0; ktc < 4; ++ktc)
#pragma unroll
        for (int r = 0; r < 4; ++r) {
          float sv = sacc[qi][ktc][r] * scale;
          if (domask && (k0 + ktc * 16 + la > qw + qi * 16 + lk * 4 + r)) sv = -1e30f;
          p[ktc][r] = sv;
          tm[r] = fmaxf(tm[r], sv);
        }
#pragma unroll
      for (int r = 0; r < 4; ++r) {
        tm[r] = fmaxf(tm[r], __shfl_xor(tm[r], 1));
        tm[r] = fmaxf(tm[r], __shfl_xor(tm[r], 2));
        tm[r] = fmaxf(tm[r], __shfl_xor(tm[r], 4));
        tm[r] = fmaxf(tm[r], __shfl_xor(tm[r], 8));
      }
      float sc_[4], ts[4];
#pragma unroll
      for (int r = 0; r < 4; ++r) {
        float mn = fmaxf(mr[qi][r], tm[r]);
        sc_[r] = __expf(mr[qi][r] - mn);
        mr[qi][r] = mn;
        ts[r] = 0.f;
      }
#pragma unroll
      for (int ktc = 0; ktc < 4; ++ktc)
#pragma unroll
        for (int r = 0; r < 4; ++r) {
          float e = __expf(p[ktc][r] - mr[qi][r]);
          p[ktc][r] = e;
          ts[r] += e;
        }
#pragma unroll
      for (int r = 0; r < 4; ++r) {
        ts[r] += __shfl_xor(ts[r], 1);
        ts[r] += __shfl_xor(ts[r], 2);
        ts[r] += __shfl_xor(ts[r], 4);
        ts[r] += __shfl_xor(ts[r], 8);
        lr[qi][r] = lr[qi][r] * sc_[r] + ts[r];
      }
#pragma unroll
      for (int dt = 0; dt < 8; ++dt)
#pragma unroll
        for (int r = 0; r < 4; ++r) oa[qi][dt][r] *= sc_[r];
      // write P (bf16) to per-wave swizzled LDS
#pragma unroll
      for (int ktc = 0; ktc < 4; ++ktc)
#pragma unroll
        for (int r = 0; r < 4; ++r) {
          int qrow = qi * 16 + lk * 4 + r;
          int k = ktc * 16 + la;
          *(unsigned short*)(pw + qrow * 128 + (((k >> 3) ^ (qrow & 7)) << 4) + ((k & 7) << 1)) =
              f2bf(p[ktc][r]);
        }
    }
    asm volatile("s_waitcnt lgkmcnt(0)" ::: "memory");

    bf16x8_t pf[2][2];
#pragma unroll
    for (int qi = 0; qi < 2; ++qi)
#pragma unroll
      for (int ks = 0; ks < 2; ++ks) {
        int row = qi * 16 + la;
        pf[qi][ks] = __builtin_bit_cast(
            bf16x8_t, *(const ushort8*)(pw + row * 128 + ((((ks << 2) + lk) ^ (row & 7)) << 4)));
      }
#pragma unroll
    for (int dt = 0; dt < 8; ++dt) {
      int d = dt * 16 + la;
#pragma unroll
      for (int ks = 0; ks < 2; ++ks) {
        bf16x8_t vf = __builtin_bit_cast(
            bf16x8_t, *(const ushort8*)(Vsb + d * 128 + ((((ks << 2) + lk) ^ (d & 7)) << 4)));
        oa[0][dt] = __builtin_amdgcn_mfma_f32_16x16x32_bf16(pf[0][ks], vf, oa[0][dt], 0, 0, 0);
        oa[1][dt] = __builtin_amdgcn_mfma_f32_16x16x32_bf16(pf[1][ks], vf, oa[1][dt], 0, 0, 0);
      }
    }
  }

#pragma unroll
  for (int qi = 0; qi < 2; ++qi) {
    float inv[4];
#pragma unroll
    for (int r = 0; r < 4; ++r) inv[r] = 1.f / lr[qi][r];
#pragma unroll
    for (int dt = 0; dt < 8; ++dt)
#pragma unroll
      for (int r = 0; r < 4; ++r)
        Ob[(size_t)(b * S + qw + qi * 16 + lk * 4 + r) * 2048 + h * 128 + dt * 16 + la] =
            f2bf(oa[qi][dt][r] * inv[r]);
  }
}

extern "C" void kernel_launch(void* const* d_in, const int* in_sizes, int n_in,
                              void* d_out, int out_size, void* d_ws, size_t ws_size,
                              hipStream_t stream) {
  const float* x = (const float*)d_in[0];
  const float* rc = (const float*)d_in[1];
  const float* rs = (const float*)d_in[2];
  const float* Wq = (const float*)d_in[3];
  const float* Wk = (const float*)d_in[4];
  const float* Wv = (const float*)d_in[5];
  const float* Wo = (const float*)d_in[6];
  float* out = (float*)d_out;

  const int B = 2, S = 2048, DM = 2048, DKV = 512;
  const int M = B * S;  // 4096

  unsigned short* Qb = (unsigned short*)d_ws;   // M x 2048
  unsigned short* Kb = Qb + (size_t)M * DM;     // M x 512
  unsigned short* Vb = Kb + (size_t)M * DKV;    // M x 512
  unsigned short* Ob = Vb + (size_t)M * DKV;    // M x 2048
  unsigned short* Vt = Ob + (size_t)M * DM;     // 1024 x 2048 (transposed V)

  dim3 blk(256);
  gemm_k<false, true><<<dim3(DM / 64, M / 64), blk, 0, stream>>>(x, Wq, Qb, M, DM, DM);
  gemm_k<false, true><<<dim3(DKV / 64, M / 64), blk, 0, stream>>>(x, Wk, Kb, M, DKV, DM);
  gemm_k<false, true><<<dim3(DKV / 64, M / 64), blk, 0, stream>>>(x, Wv, Vb, M, DKV, DM);

  int totq = M * (DM / 2);
  rope_k<<<(totq + 255) / 256, blk, 0, stream>>>(Qb, rc, rs, 10, DM, totq);
  int totk = M * (DKV / 2);
  rope_k<<<(totk + 255) / 256, blk, 0, stream>>>(Kb, rc, rs, 8, DKV, totk);

  transpose_v<<<dim3(S / 32, 128 / 32, B * 4), dim3(32, 8), 0, stream>>>(Vb, Vt);

  attn_mfma<<<dim3(S / 128, 16, B), blk, 0, stream>>>(Qb, Kb, Vt, Ob);

  gemm_k<true, false><<<dim3(DM / 64, M / 64), blk, 0, stream>>>(Ob, Wo, out, M, DM, DM);
}

// Round 3
// 421.318 us; speedup vs baseline: 4.8126x; 1.7591x over previous
//
#include <hip/hip_runtime.h>
#include <hip/hip_bf16.h>
#include <math.h>

typedef __bf16 bf16x8_t __attribute__((ext_vector_type(8)));
typedef float f32x4 __attribute__((ext_vector_type(4)));
typedef unsigned short ushort8 __attribute__((ext_vector_type(8)));

__device__ inline unsigned short f2bf(float f) {
  unsigned int u = __builtin_bit_cast(unsigned int, f);
  u += 0x7fffu + ((u >> 16) & 1u);
  return (unsigned short)(u >> 16);
}
__device__ inline float b2f(unsigned short s) {
  unsigned int u = ((unsigned int)s) << 16;
  return __builtin_bit_cast(float, u);
}

__device__ __forceinline__ void gll16(const void* g, void* l) {
  __builtin_amdgcn_global_load_lds((const __attribute__((address_space(1))) void*)g,
                                   (__attribute__((address_space(3))) void*)l, 16, 0, 0);
}

// ---------- prepass: fp32 -> bf16 convert ----------
__global__ void cvt_k(const float* __restrict__ X, unsigned short* __restrict__ Xb, int total8) {
  int i = blockIdx.x * blockDim.x + threadIdx.x;
  if (i >= total8) return;
  const float4* p = (const float4*)X + 2 * (size_t)i;
  float4 a = p[0], b = p[1];
  ushort8 v;
  v[0] = f2bf(a.x); v[1] = f2bf(a.y); v[2] = f2bf(a.z); v[3] = f2bf(a.w);
  v[4] = f2bf(b.x); v[5] = f2bf(b.y); v[6] = f2bf(b.z); v[7] = f2bf(b.w);
  ((ushort8*)Xb)[i] = v;
}

// ---------- prepass: transpose + convert: Wt[n][k] = bf16(W[k][n]), W: K x N fp32 ----------
__global__ void twc_k(const float* __restrict__ W, unsigned short* __restrict__ Wt, int K, int N) {
  __shared__ float tile[32][33];
  int k0 = blockIdx.x * 32, n0 = blockIdx.y * 32;
  int tx = threadIdx.x, ty = threadIdx.y;  // 32 x 8
#pragma unroll
  for (int i = 0; i < 32; i += 8) tile[ty + i][tx] = W[(size_t)(k0 + ty + i) * N + n0 + tx];
  __syncthreads();
#pragma unroll
  for (int i = 0; i < 32; i += 8)
    Wt[(size_t)(n0 + ty + i) * K + k0 + tx] = f2bf(tile[tx][ty + i]);
}

// ---------- m97-style GEMM: C[M][N] = A[M][K] @ Bt[N][K]^T, bf16 in, bf16/fp32 out ----------
// 128x128 tile, BK=32, 4 waves (2x2), global_load_lds width-16 staging, linear LDS.
template <bool OUT_BF16>
__global__ __launch_bounds__(256) void gemm_tn(const unsigned short* __restrict__ A,
                                               const unsigned short* __restrict__ Bt,
                                               void* __restrict__ Cv, int M, int N, int K) {
  __shared__ __align__(16) unsigned short As[128 * 32];
  __shared__ __align__(16) unsigned short Bs[128 * 32];
  const int t = threadIdx.x, w = t >> 6, lane = t & 63;
  const int la = lane & 15, lk = lane >> 4;
  const int wr = w >> 1, wc = w & 1;
  const int bm = blockIdx.y * 128, bn = blockIdx.x * 128;
  const int lrow = lane >> 2, lcb = (lane & 3) * 8;  // within-chunk: row 0..15, col elem 0..31

  f32x4 acc[4][4] = {};

  for (int k0 = 0; k0 < K; k0 += 32) {
    // stage A (8 chunks of 16 rows x 32 cols) + B: each wave 2 chunks of each
#pragma unroll
    for (int u = 0; u < 2; ++u) {
      int c = w * 2 + u;
      gll16(A + (size_t)(bm + c * 16 + lrow) * K + k0 + lcb, (char*)As + c * 1024);
      gll16(Bt + (size_t)(bn + c * 16 + lrow) * K + k0 + lcb, (char*)Bs + c * 1024);
    }
    __syncthreads();

    bf16x8_t a[4], b[4];
#pragma unroll
    for (int m = 0; m < 4; ++m)
      a[m] = __builtin_bit_cast(bf16x8_t,
                                *(const ushort8*)(As + (wr * 64 + m * 16 + la) * 32 + lk * 8));
#pragma unroll
    for (int n = 0; n < 4; ++n)
      b[n] = __builtin_bit_cast(bf16x8_t,
                                *(const ushort8*)(Bs + (wc * 64 + n * 16 + la) * 32 + lk * 8));
#pragma unroll
    for (int m = 0; m < 4; ++m)
#pragma unroll
      for (int n = 0; n < 4; ++n)
        acc[m][n] = __builtin_amdgcn_mfma_f32_16x16x32_bf16(a[m], b[n], acc[m][n], 0, 0, 0);
    __syncthreads();
  }

#pragma unroll
  for (int m = 0; m < 4; ++m) {
#pragma unroll
    for (int n = 0; n < 4; ++n) {
#pragma unroll
      for (int r = 0; r < 4; ++r) {
        int row = bm + wr * 64 + m * 16 + lk * 4 + r;
        int col = bn + wc * 64 + n * 16 + la;
        if (OUT_BF16)
          ((unsigned short*)Cv)[(size_t)row * N + col] = f2bf(acc[m][n][r]);
        else
          ((float*)Cv)[(size_t)row * N + col] = acc[m][n][r];
      }
    }
  }
}

// ---------- RoPE (in-place on bf16, heads of 128, pairs interleaved) ----------
__global__ void rope_k(unsigned short* X, const float* __restrict__ cs,
                       const float* __restrict__ sn, int log2ppr, int rowlen, int total) {
  int idx = blockIdx.x * blockDim.x + threadIdx.x;
  if (idx >= total) return;
  int row = idx >> log2ppr;
  int p = idx & ((1 << log2ppr) - 1);
  int h = p >> 6, i = p & 63;
  int s = row & 2047;
  float c = cs[s * 64 + i], sv = sn[s * 64 + i];
  unsigned short* base = X + (size_t)row * rowlen + h * 128 + 2 * i;
  float e = b2f(base[0]), o = b2f(base[1]);
  base[0] = f2bf(e * c - o * sv);
  base[1] = f2bf(e * sv + o * c);
}

// ---------- V transpose: Vt[(b*4+g)*128 + d][s] = KV[(b*2048+s)*1024 + 512 + g*128 + d] ----------
__global__ void transpose_v(const unsigned short* __restrict__ KV, unsigned short* __restrict__ Vt) {
  __shared__ unsigned short tile[32][33];
  int bg = blockIdx.z;
  int b = bg >> 2, g = bg & 3;
  int s0 = blockIdx.x * 32, d0 = blockIdx.y * 32;
  int tx = threadIdx.x, ty = threadIdx.y;  // 32 x 8
#pragma unroll
  for (int i = 0; i < 32; i += 8)
    tile[ty + i][tx] = KV[((size_t)(b * 2048 + s0 + ty + i)) * 1024 + 512 + g * 128 + d0 + tx];
  __syncthreads();
#pragma unroll
  for (int i = 0; i < 32; i += 8)
    Vt[((size_t)(bg * 128 + d0 + ty + i)) * 2048 + s0 + tx] = tile[tx][ty + i];
}

// ---------- MFMA flash attention ----------
// grid (S/128, 16 heads, B), block 256 (4 waves x 32 q-rows). Heavy q-tiles first.
__global__ __launch_bounds__(256) void attn_mfma(const unsigned short* __restrict__ Qb,
                                                 const unsigned short* __restrict__ KVb,
                                                 const unsigned short* __restrict__ Vt,
                                                 unsigned short* __restrict__ Ob) {
  const int S = 2048;
  __shared__ __align__(16) unsigned short KsA[64 * 128];
  __shared__ __align__(16) unsigned short VsA[128 * 64];
  __shared__ __align__(16) unsigned short PsA[4 * 32 * 64];
  char* Ksb = (char*)KsA;
  char* Vsb = (char*)VsA;

  const int t = threadIdx.x;
  const int w = t >> 6, lane = t & 63;
  const int la = lane & 15, lk = lane >> 4;
  const int b = blockIdx.z, h = blockIdx.y, g = h >> 2;
  const int qt = gridDim.x - 1 - blockIdx.x;  // heavy tiles dispatch first
  const int q0 = qt * 128;
  const int qw = q0 + w * 32;
  const float scale = 0.08838834764831845f;  // 1/sqrt(128)

  bf16x8_t qf[2][4];
#pragma unroll
  for (int qi = 0; qi < 2; ++qi)
#pragma unroll
    for (int dt = 0; dt < 4; ++dt)
      qf[qi][dt] = __builtin_bit_cast(
          bf16x8_t, *(const ushort8*)(Qb + (size_t)(b * S + qw + qi * 16 + la) * 2048 + h * 128 +
                                      dt * 32 + lk * 8));

  f32x4 oa[2][8];
#pragma unroll
  for (int qi = 0; qi < 2; ++qi)
#pragma unroll
    for (int dt = 0; dt < 8; ++dt) oa[qi][dt] = (f32x4){0.f, 0.f, 0.f, 0.f};
  float mr[2][4], lr[2][4];
#pragma unroll
  for (int qi = 0; qi < 2; ++qi)
#pragma unroll
    for (int r = 0; r < 4; ++r) {
      mr[qi][r] = -1e30f;
      lr[qi][r] = 0.f;
    }

  const int n_kt = 2 * qt + 2;
  const int krow = t >> 2, kc0 = (t & 3) * 4;
  const int vrow = t >> 1, vc0 = (t & 1) * 4;
  char* pw = (char*)PsA + w * 4096;

  for (int kt = 0; kt < n_kt; ++kt) {
    const int k0 = kt * 64;
    __syncthreads();
    {
      const unsigned short* ksrc = KVb + (size_t)(b * S + k0 + krow) * 1024 + g * 128;
#pragma unroll
      for (int u = 0; u < 4; ++u) {
        int c = kc0 + u;
        *(ushort8*)(Ksb + krow * 256 + (((c ^ (krow & 7))) << 4)) = *(const ushort8*)(ksrc + c * 8);
      }
      const unsigned short* vsrc = Vt + (size_t)((b * 4 + g) * 128 + vrow) * 2048 + k0;
#pragma unroll
      for (int u = 0; u < 4; ++u) {
        int c = vc0 + u;
        *(ushort8*)(Vsb + vrow * 128 + (((c ^ (vrow & 7))) << 4)) = *(const ushort8*)(vsrc + c * 8);
      }
    }
    __syncthreads();

    if (k0 > qw + 31) continue;

    f32x4 sacc[2][4];
#pragma unroll
    for (int qi = 0; qi < 2; ++qi)
#pragma unroll
      for (int ktc = 0; ktc < 4; ++ktc) sacc[qi][ktc] = (f32x4){0.f, 0.f, 0.f, 0.f};
#pragma unroll
    for (int ktc = 0; ktc < 4; ++ktc) {
      int row = ktc * 16 + la;
#pragma unroll
      for (int dt = 0; dt < 4; ++dt) {
        bf16x8_t kf = __builtin_bit_cast(
            bf16x8_t, *(const ushort8*)(Ksb + row * 256 + ((((dt << 2) + lk) ^ (row & 7)) << 4)));
        sacc[0][ktc] = __builtin_amdgcn_mfma_f32_16x16x32_bf16(qf[0][dt], kf, sacc[0][ktc], 0, 0, 0);
        sacc[1][ktc] = __builtin_amdgcn_mfma_f32_16x16x32_bf16(qf[1][dt], kf, sacc[1][ktc], 0, 0, 0);
      }
    }

    const bool domask = (kt >= n_kt - 2);
#pragma unroll
    for (int qi = 0; qi < 2; ++qi) {
      float p[4][4], tm[4];
#pragma unroll
      for (int r = 0; r < 4; ++r) tm[r] = -1e30f;
#pragma unroll
      for (int ktc = 0; ktc < 4; ++ktc)
#pragma unroll
        for (int r = 0; r < 4; ++r) {
          float sv = sacc[qi][ktc][r] * scale;
          if (domask && (k0 + ktc * 16 + la > qw + qi * 16 + lk * 4 + r)) sv = -1e30f;
          p[ktc][r] = sv;
          tm[r] = fmaxf(tm[r], sv);
        }
#pragma unroll
      for (int r = 0; r < 4; ++r) {
        tm[r] = fmaxf(tm[r], __shfl_xor(tm[r], 1));
        tm[r] = fmaxf(tm[r], __shfl_xor(tm[r], 2));
        tm[r] = fmaxf(tm[r], __shfl_xor(tm[r], 4));
        tm[r] = fmaxf(tm[r], __shfl_xor(tm[r], 8));
      }
      float sc_[4], ts[4];
#pragma unroll
      for (int r = 0; r < 4; ++r) {
        float mn = fmaxf(mr[qi][r], tm[r]);
        sc_[r] = __expf(mr[qi][r] - mn);
        mr[qi][r] = mn;
        ts[r] = 0.f;
      }
#pragma unroll
      for (int ktc = 0; ktc < 4; ++ktc)
#pragma unroll
        for (int r = 0; r < 4; ++r) {
          float e = __expf(p[ktc][r] - mr[qi][r]);
          p[ktc][r] = e;
          ts[r] += e;
        }
#pragma unroll
      for (int r = 0; r < 4; ++r) {
        ts[r] += __shfl_xor(ts[r], 1);
        ts[r] += __shfl_xor(ts[r], 2);
        ts[r] += __shfl_xor(ts[r], 4);
        ts[r] += __shfl_xor(ts[r], 8);
        lr[qi][r] = lr[qi][r] * sc_[r] + ts[r];
      }
#pragma unroll
      for (int dt = 0; dt < 8; ++dt)
#pragma unroll
        for (int r = 0; r < 4; ++r) oa[qi][dt][r] *= sc_[r];
#pragma unroll
      for (int ktc = 0; ktc < 4; ++ktc)
#pragma unroll
        for (int r = 0; r < 4; ++r) {
          int qrow = qi * 16 + lk * 4 + r;
          int k = ktc * 16 + la;
          *(unsigned short*)(pw + qrow * 128 + (((k >> 3) ^ (qrow & 7)) << 4) + ((k & 7) << 1)) =
              f2bf(p[ktc][r]);
        }
    }
    asm volatile("s_waitcnt lgkmcnt(0)" ::: "memory");

    bf16x8_t pf[2][2];
#pragma unroll
    for (int qi = 0; qi < 2; ++qi)
#pragma unroll
      for (int ks = 0; ks < 2; ++ks) {
        int row = qi * 16 + la;
        pf[qi][ks] = __builtin_bit_cast(
            bf16x8_t, *(const ushort8*)(pw + row * 128 + ((((ks << 2) + lk) ^ (row & 7)) << 4)));
      }
#pragma unroll
    for (int dt = 0; dt < 8; ++dt) {
      int d = dt * 16 + la;
#pragma unroll
      for (int ks = 0; ks < 2; ++ks) {
        bf16x8_t vf = __builtin_bit_cast(
            bf16x8_t, *(const ushort8*)(Vsb + d * 128 + ((((ks << 2) + lk) ^ (d & 7)) << 4)));
        oa[0][dt] = __builtin_amdgcn_mfma_f32_16x16x32_bf16(pf[0][ks], vf, oa[0][dt], 0, 0, 0);
        oa[1][dt] = __builtin_amdgcn_mfma_f32_16x16x32_bf16(pf[1][ks], vf, oa[1][dt], 0, 0, 0);
      }
    }
  }

#pragma unroll
  for (int qi = 0; qi < 2; ++qi) {
    float inv[4];
#pragma unroll
    for (int r = 0; r < 4; ++r) inv[r] = 1.f / lr[qi][r];
#pragma unroll
    for (int dt = 0; dt < 8; ++dt)
#pragma unroll
      for (int r = 0; r < 4; ++r)
        Ob[(size_t)(b * S + qw + qi * 16 + lk * 4 + r) * 2048 + h * 128 + dt * 16 + la] =
            f2bf(oa[qi][dt][r] * inv[r]);
  }
}

extern "C" void kernel_launch(void* const* d_in, const int* in_sizes, int n_in,
                              void* d_out, int out_size, void* d_ws, size_t ws_size,
                              hipStream_t stream) {
  const float* x = (const float*)d_in[0];
  const float* rc = (const float*)d_in[1];
  const float* rs = (const float*)d_in[2];
  const float* Wq = (const float*)d_in[3];
  const float* Wk = (const float*)d_in[4];
  const float* Wv = (const float*)d_in[5];
  const float* Wo = (const float*)d_in[6];
  float* out = (float*)d_out;

  const int B = 2, S = 2048, DM = 2048;
  const int M = B * S;  // 4096

  // workspace layout (bf16 elements); Ob aliases xb, WoT aliases WqT (stream-ordered)
  unsigned short* xb = (unsigned short*)d_ws;          // M x 2048   (16 MB)
  unsigned short* Qb = xb + (size_t)M * DM;            // M x 2048   (16 MB)
  unsigned short* KVb = Qb + (size_t)M * DM;           // M x 1024   (8 MB)
  unsigned short* Vt = KVb + (size_t)M * 1024;         // 1024 x 2048 (4 MB)
  unsigned short* WqT = Vt + (size_t)1024 * 2048;      // 2048 x 2048 (8 MB)
  unsigned short* WkvT = WqT + (size_t)DM * DM;        // 1024 x 2048 (4 MB)
  unsigned short* Ob = xb;                              // alias: x dead after projections
  unsigned short* WoT = WqT;                            // alias: WqT dead after Q proj

  dim3 blk(256);

  // prepass conversions
  cvt_k<<<(M * DM / 8 + 255) / 256, blk, 0, stream>>>(x, xb, M * DM / 8);
  twc_k<<<dim3(DM / 32, DM / 32), dim3(32, 8), 0, stream>>>(Wq, WqT, DM, DM);
  twc_k<<<dim3(DM / 32, 512 / 32), dim3(32, 8), 0, stream>>>(Wk, WkvT, DM, 512);
  twc_k<<<dim3(DM / 32, 512 / 32), dim3(32, 8), 0, stream>>>(Wv, WkvT + (size_t)512 * DM, DM, 512);

  // projections
  gemm_tn<true><<<dim3(DM / 128, M / 128), blk, 0, stream>>>(xb, WqT, Qb, M, DM, DM);
  gemm_tn<true><<<dim3(1024 / 128, M / 128), blk, 0, stream>>>(xb, WkvT, KVb, M, 1024, DM);

  // Wo transpose (after Q proj; overwrites WqT region)
  twc_k<<<dim3(DM / 32, DM / 32), dim3(32, 8), 0, stream>>>(Wo, WoT, DM, DM);

  // RoPE
  int totq = M * (DM / 2);
  rope_k<<<(totq + 255) / 256, blk, 0, stream>>>(Qb, rc, rs, 10, DM, totq);
  int totk = M * 256;
  rope_k<<<(totk + 255) / 256, blk, 0, stream>>>(KVb, rc, rs, 8, 1024, totk);

  transpose_v<<<dim3(S / 32, 128 / 32, B * 4), dim3(32, 8), 0, stream>>>(KVb, Vt);

  attn_mfma<<<dim3(S / 128, 16, B), blk, 0, stream>>>(Qb, KVb, Vt, Ob);

  gemm_tn<false><<<dim3(DM / 128, M / 128), blk, 0, stream>>>(Ob, WoT, out, M, DM, DM);
}

// Round 5
// 361.332 us; speedup vs baseline: 5.6115x; 1.1660x over previous
//
#include <hip/hip_runtime.h>
#include <hip/hip_bf16.h>
#include <math.h>

typedef __bf16 bf16x8_t __attribute__((ext_vector_type(8)));
typedef float f32x4 __attribute__((ext_vector_type(4)));
typedef unsigned short ushort8 __attribute__((ext_vector_type(8)));

__device__ inline unsigned short f2bf(float f) {
  unsigned int u = __builtin_bit_cast(unsigned int, f);
  u += 0x7fffu + ((u >> 16) & 1u);
  return (unsigned short)(u >> 16);
}
__device__ inline float b2f(unsigned short s) {
  unsigned int u = ((unsigned int)s) << 16;
  return __builtin_bit_cast(float, u);
}

__device__ __forceinline__ void gll16(const void* g, void* l) {
  __builtin_amdgcn_global_load_lds((const __attribute__((address_space(1))) void*)g,
                                   (__attribute__((address_space(3))) void*)l, 16, 0, 0);
}

// ---------- prepass: fp32 -> bf16 convert ----------
__global__ void cvt_k(const float* __restrict__ X, unsigned short* __restrict__ Xb, int total8) {
  int i = blockIdx.x * blockDim.x + threadIdx.x;
  if (i >= total8) return;
  const float4* p = (const float4*)X + 2 * (size_t)i;
  float4 a = p[0], b = p[1];
  ushort8 v;
  v[0] = f2bf(a.x); v[1] = f2bf(a.y); v[2] = f2bf(a.z); v[3] = f2bf(a.w);
  v[4] = f2bf(b.x); v[5] = f2bf(b.y); v[6] = f2bf(b.z); v[7] = f2bf(b.w);
  ((ushort8*)Xb)[i] = v;
}

// ---------- prepass: transpose + convert: Wt[n][k] = bf16(W[k][n]), W: K x N fp32, Wt stride 2048 ----------
__global__ void twc_k(const float* __restrict__ W, unsigned short* __restrict__ Wt, int K, int N) {
  __shared__ float tile[32][33];
  int k0 = blockIdx.x * 32, n0 = blockIdx.y * 32;
  int tx = threadIdx.x, ty = threadIdx.y;  // 32 x 8
#pragma unroll
  for (int i = 0; i < 32; i += 8) tile[ty + i][tx] = W[(size_t)(k0 + ty + i) * N + n0 + tx];
  __syncthreads();
#pragma unroll
  for (int i = 0; i < 32; i += 8)
    Wt[(size_t)(n0 + ty + i) * K + k0 + tx] = f2bf(tile[tx][ty + i]);
}

// ---------- m97-style GEMM: C[M][N] = A[M][K] @ Bt[N][K]^T ----------
template <bool OUT_BF16>
__global__ __launch_bounds__(256) void gemm_tn(const unsigned short* __restrict__ A,
                                               const unsigned short* __restrict__ Bt,
                                               void* __restrict__ Cv, int M, int N, int K) {
  __shared__ __align__(16) unsigned short As[128 * 32];
  __shared__ __align__(16) unsigned short Bs[128 * 32];
  const int t = threadIdx.x, w = t >> 6, lane = t & 63;
  const int la = lane & 15, lk = lane >> 4;
  const int wr = w >> 1, wc = w & 1;
  const int bm = blockIdx.y * 128, bn = blockIdx.x * 128;
  const int lrow = lane >> 2, lcb = (lane & 3) * 8;

  f32x4 acc[4][4] = {};

  for (int k0 = 0; k0 < K; k0 += 32) {
#pragma unroll
    for (int u = 0; u < 2; ++u) {
      int c = w * 2 + u;
      gll16(A + (size_t)(bm + c * 16 + lrow) * K + k0 + lcb, (char*)As + c * 1024);
      gll16(Bt + (size_t)(bn + c * 16 + lrow) * K + k0 + lcb, (char*)Bs + c * 1024);
    }
    __syncthreads();

    bf16x8_t a[4], b[4];
#pragma unroll
    for (int m = 0; m < 4; ++m)
      a[m] = __builtin_bit_cast(bf16x8_t,
                                *(const ushort8*)(As + (wr * 64 + m * 16 + la) * 32 + lk * 8));
#pragma unroll
    for (int n = 0; n < 4; ++n)
      b[n] = __builtin_bit_cast(bf16x8_t,
                                *(const ushort8*)(Bs + (wc * 64 + n * 16 + la) * 32 + lk * 8));
#pragma unroll
    for (int m = 0; m < 4; ++m)
#pragma unroll
      for (int n = 0; n < 4; ++n)
        acc[m][n] = __builtin_amdgcn_mfma_f32_16x16x32_bf16(a[m], b[n], acc[m][n], 0, 0, 0);
    __syncthreads();
  }

#pragma unroll
  for (int m = 0; m < 4; ++m) {
#pragma unroll
    for (int n = 0; n < 4; ++n) {
#pragma unroll
      for (int r = 0; r < 4; ++r) {
        int row = bm + wr * 64 + m * 16 + lk * 4 + r;
        int col = bn + wc * 64 + n * 16 + la;
        if (OUT_BF16)
          ((unsigned short*)Cv)[(size_t)row * N + col] = f2bf(acc[m][n][r]);
        else
          ((float*)Cv)[(size_t)row * N + col] = acc[m][n][r];
      }
    }
  }
}

// ---------- RoPE (in-place bf16; rowlen stride; log2ppr pairs per row) ----------
__global__ void rope_k(unsigned short* X, const float* __restrict__ cs,
                       const float* __restrict__ sn, int log2ppr, int rowlen, int total) {
  int idx = blockIdx.x * blockDim.x + threadIdx.x;
  if (idx >= total) return;
  int row = idx >> log2ppr;
  int p = idx & ((1 << log2ppr) - 1);
  int h = p >> 6, i = p & 63;
  int s = row & 2047;
  float c = cs[s * 64 + i], sv = sn[s * 64 + i];
  unsigned short* base = X + (size_t)row * rowlen + h * 128 + 2 * i;
  float e = b2f(base[0]), o = b2f(base[1]);
  base[0] = f2bf(e * c - o * sv);
  base[1] = f2bf(e * sv + o * c);
}

// ---------- V transpose from QKV: Vt[(b*4+g)*128 + d][s] = QKV[(b*2048+s)*3072 + 2560 + g*128 + d] ----------
__global__ void transpose_v(const unsigned short* __restrict__ QKV, unsigned short* __restrict__ Vt) {
  __shared__ unsigned short tile[32][33];
  int bg = blockIdx.z;
  int b = bg >> 2, g = bg & 3;
  int s0 = blockIdx.x * 32, d0 = blockIdx.y * 32;
  int tx = threadIdx.x, ty = threadIdx.y;  // 32 x 8
#pragma unroll
  for (int i = 0; i < 32; i += 8)
    tile[ty + i][tx] = QKV[((size_t)(b * 2048 + s0 + ty + i)) * 3072 + 2560 + g * 128 + d0 + tx];
  __syncthreads();
#pragma unroll
  for (int i = 0; i < 32; i += 8)
    Vt[((size_t)(bg * 128 + d0 + ty + i)) * 2048 + s0 + tx] = tile[tx][ty + i];
}

// ---------- MFMA flash attention: 8 waves x 16 q-rows, kv-tile 64 ----------
// grid (S/128, 16 heads, B), block 512.
__global__ __launch_bounds__(512) void attn_mfma(const unsigned short* __restrict__ QKV,
                                                 const unsigned short* __restrict__ Vt,
                                                 unsigned short* __restrict__ Ob) {
  const int S = 2048;
  __shared__ __align__(16) unsigned short KsA[64 * 128];   // swizzled [krow][d]
  __shared__ __align__(16) unsigned short VsA[128 * 64];   // swizzled [d][kv]
  __shared__ __align__(16) unsigned short PsA[8 * 16 * 64]; // per-wave P
  char* Ksb = (char*)KsA;
  char* Vsb = (char*)VsA;

  const int t = threadIdx.x;
  const int w = t >> 6, lane = t & 63;
  const int la = lane & 15, lk = lane >> 4;
  const int b = blockIdx.z, h = blockIdx.y, g = h >> 2;
  const int qt = gridDim.x - 1 - blockIdx.x;  // heavy tiles first
  const int q0 = qt * 128;
  const int qw = q0 + w * 16;
  const float scale = 0.08838834764831845f;  // 1/sqrt(128)

  // Q fragments: A-frag row = la, k elems = dt*32 + lk*8 + i
  bf16x8_t qf[4];
#pragma unroll
  for (int dt = 0; dt < 4; ++dt)
    qf[dt] = __builtin_bit_cast(
        bf16x8_t,
        *(const ushort8*)(QKV + (size_t)(b * S + qw + la) * 3072 + h * 128 + dt * 32 + lk * 8));

  f32x4 oa[8];
#pragma unroll
  for (int dt = 0; dt < 8; ++dt) oa[dt] = (f32x4){0.f, 0.f, 0.f, 0.f};
  float mr[4], lr[4];
#pragma unroll
  for (int r = 0; r < 4; ++r) {
    mr[r] = -1e30f;
    lr[r] = 0.f;
  }

  const int n_kt = 2 * qt + 2;
  const int krow = t >> 3, kc0 = (t & 7) * 2;  // K: 64 rows x 16 chunks, 2/thread
  const int vrow = t >> 2, vc0 = (t & 3) * 2;  // V: 128 rows x 8 chunks, 2/thread
  const int kmask0 = qw & ~63;                 // the single partially-masked kv tile
  char* pw = (char*)PsA + w * 2048;

  for (int kt = 0; kt < n_kt; ++kt) {
    const int k0 = kt * 64;
    __syncthreads();
    {
      const unsigned short* ksrc = QKV + (size_t)(b * S + k0 + krow) * 3072 + 2048 + g * 128;
#pragma unroll
      for (int u = 0; u < 2; ++u) {
        int c = kc0 + u;
        *(ushort8*)(Ksb + krow * 256 + ((c ^ (krow & 7)) << 4)) = *(const ushort8*)(ksrc + c * 8);
      }
      const unsigned short* vsrc = Vt + (size_t)((b * 4 + g) * 128 + vrow) * 2048 + k0;
#pragma unroll
      for (int u = 0; u < 2; ++u) {
        int c = vc0 + u;
        *(ushort8*)(Vsb + vrow * 128 + ((c ^ (vrow & 7)) << 4)) = *(const ushort8*)(vsrc + c * 8);
      }
    }
    __syncthreads();

    if (k0 > qw + 15) continue;  // fully masked for this wave

    // QK^T: C rows = q (lk*4+r), cols = k (ktc*16+la)
    f32x4 sacc[4];
#pragma unroll
    for (int ktc = 0; ktc < 4; ++ktc) sacc[ktc] = (f32x4){0.f, 0.f, 0.f, 0.f};
    __builtin_amdgcn_s_setprio(1);
#pragma unroll
    for (int ktc = 0; ktc < 4; ++ktc) {
      int row = ktc * 16 + la;
#pragma unroll
      for (int dt = 0; dt < 4; ++dt) {
        bf16x8_t kf = __builtin_bit_cast(
            bf16x8_t, *(const ushort8*)(Ksb + row * 256 + ((((dt << 2) + lk) ^ (row & 7)) << 4)));
        sacc[ktc] = __builtin_amdgcn_mfma_f32_16x16x32_bf16(qf[dt], kf, sacc[ktc], 0, 0, 0);
      }
    }
    __builtin_amdgcn_s_setprio(0);

    const bool domask = (k0 == kmask0);
    float p[4][4], tm[4];
#pragma unroll
    for (int r = 0; r < 4; ++r) tm[r] = -1e30f;
#pragma unroll
    for (int ktc = 0; ktc < 4; ++ktc)
#pragma unroll
      for (int r = 0; r < 4; ++r) {
        float sv = sacc[ktc][r] * scale;
        if (domask && (k0 + ktc * 16 + la > qw + lk * 4 + r)) sv = -1e30f;
        p[ktc][r] = sv;
        tm[r] = fmaxf(tm[r], sv);
      }
#pragma unroll
    for (int r = 0; r < 4; ++r) {
      tm[r] = fmaxf(tm[r], __shfl_xor(tm[r], 1));
      tm[r] = fmaxf(tm[r], __shfl_xor(tm[r], 2));
      tm[r] = fmaxf(tm[r], __shfl_xor(tm[r], 4));
      tm[r] = fmaxf(tm[r], __shfl_xor(tm[r], 8));
    }
    float sc_[4], ts[4];
#pragma unroll
    for (int r = 0; r < 4; ++r) {
      float mn = fmaxf(mr[r], tm[r]);
      sc_[r] = __expf(mr[r] - mn);
      mr[r] = mn;
      ts[r] = 0.f;
    }
#pragma unroll
    for (int ktc = 0; ktc < 4; ++ktc)
#pragma unroll
      for (int r = 0; r < 4; ++r) {
        float e = __expf(p[ktc][r] - mr[r]);
        p[ktc][r] = e;
        ts[r] += e;
      }
#pragma unroll
    for (int r = 0; r < 4; ++r) {
      ts[r] += __shfl_xor(ts[r], 1);
      ts[r] += __shfl_xor(ts[r], 2);
      ts[r] += __shfl_xor(ts[r], 4);
      ts[r] += __shfl_xor(ts[r], 8);
      lr[r] = lr[r] * sc_[r] + ts[r];
    }
#pragma unroll
    for (int dt = 0; dt < 8; ++dt)
#pragma unroll
      for (int r = 0; r < 4; ++r) oa[dt][r] *= sc_[r];
    // write P (bf16) to per-wave swizzled LDS
#pragma unroll
    for (int ktc = 0; ktc < 4; ++ktc)
#pragma unroll
      for (int r = 0; r < 4; ++r) {
        int qrow = lk * 4 + r;
        int k = ktc * 16 + la;
        *(unsigned short*)(pw + qrow * 128 + (((k >> 3) ^ (qrow & 7)) << 4) + ((k & 7) << 1)) =
            f2bf(p[ktc][r]);
      }
    asm volatile("s_waitcnt lgkmcnt(0)" ::: "memory");

    bf16x8_t pf[2];
#pragma unroll
    for (int ks = 0; ks < 2; ++ks)
      pf[ks] = __builtin_bit_cast(
          bf16x8_t, *(const ushort8*)(pw + la * 128 + ((((ks << 2) + lk) ^ (la & 7)) << 4)));
    __builtin_amdgcn_s_setprio(1);
#pragma unroll
    for (int dt = 0; dt < 8; ++dt) {
      int d = dt * 16 + la;
#pragma unroll
      for (int ks = 0; ks < 2; ++ks) {
        bf16x8_t vf = __builtin_bit_cast(
            bf16x8_t, *(const ushort8*)(Vsb + d * 128 + ((((ks << 2) + lk) ^ (d & 7)) << 4)));
        oa[dt] = __builtin_amdgcn_mfma_f32_16x16x32_bf16(pf[ks], vf, oa[dt], 0, 0, 0);
      }
    }
    __builtin_amdgcn_s_setprio(0);
  }

  float inv[4];
#pragma unroll
  for (int r = 0; r < 4; ++r) inv[r] = 1.f / lr[r];
#pragma unroll
  for (int dt = 0; dt < 8; ++dt)
#pragma unroll
    for (int r = 0; r < 4; ++r)
      Ob[(size_t)(b * S + qw + lk * 4 + r) * 2048 + h * 128 + dt * 16 + la] =
          f2bf(oa[dt][r] * inv[r]);
}

extern "C" void kernel_launch(void* const* d_in, const int* in_sizes, int n_in,
                              void* d_out, int out_size, void* d_ws, size_t ws_size,
                              hipStream_t stream) {
  const float* x = (const float*)d_in[0];
  const float* rc = (const float*)d_in[1];
  const float* rs = (const float*)d_in[2];
  const float* Wq = (const float*)d_in[3];
  const float* Wk = (const float*)d_in[4];
  const float* Wv = (const float*)d_in[5];
  const float* Wo = (const float*)d_in[6];
  float* out = (float*)d_out;

  const int B = 2, S = 2048, DM = 2048;
  const int M = B * S;  // 4096

  // workspace (bf16 elems): xb | QKV | WallT (later WoT + Vt)
  unsigned short* xb = (unsigned short*)d_ws;              // M x 2048      (16 MB)
  unsigned short* QKV = xb + (size_t)M * DM;               // M x 3072      (25.2 MB)
  unsigned short* WallT = QKV + (size_t)M * 3072;          // 3072 x 2048   (12.6 MB)
  unsigned short* WoT = WallT;                             // alias (after QKV proj)
  unsigned short* Vt = WallT + (size_t)2048 * 2048;        // 1024 x 2048 (4 MB, in dead Wk/Wv rows)
  unsigned short* Ob = xb;                                 // alias (x dead after proj)

  dim3 blk(256);

  // prepass
  cvt_k<<<(M * DM / 8 + 255) / 256, blk, 0, stream>>>(x, xb, M * DM / 8);
  twc_k<<<dim3(64, 64), dim3(32, 8), 0, stream>>>(Wq, WallT, DM, DM);
  twc_k<<<dim3(64, 16), dim3(32, 8), 0, stream>>>(Wk, WallT + (size_t)2048 * DM, DM, 512);
  twc_k<<<dim3(64, 16), dim3(32, 8), 0, stream>>>(Wv, WallT + (size_t)2560 * DM, DM, 512);

  // fused QKV projection: [M,2048] @ [2048,3072]
  gemm_tn<true><<<dim3(3072 / 128, M / 128), blk, 0, stream>>>(xb, WallT, QKV, M, 3072, DM);

  // Wo transpose (overwrites WallT rows 0..2047)
  twc_k<<<dim3(64, 64), dim3(32, 8), 0, stream>>>(Wo, WoT, DM, DM);

  // RoPE: Q part (1024 pairs/row), K part (256 pairs/row)
  int totq = M * 1024;
  rope_k<<<(totq + 255) / 256, blk, 0, stream>>>(QKV, rc, rs, 10, 3072, totq);
  int totk = M * 256;
  rope_k<<<(totk + 255) / 256, blk, 0, stream>>>(QKV + 2048, rc, rs, 8, 3072, totk);

  transpose_v<<<dim3(S / 32, 4, B * 4), dim3(32, 8), 0, stream>>>(QKV, Vt);

  attn_mfma<<<dim3(S / 128, 16, B), dim3(512), 0, stream>>>(QKV, Vt, Ob);

  gemm_tn<false><<<dim3(DM / 128, M / 128), blk, 0, stream>>>(Ob, WoT, out, M, DM, DM);
}

// Round 6
// 331.518 us; speedup vs baseline: 6.1162x; 1.0899x over previous
//
#include <hip/hip_runtime.h>
#include <hip/hip_bf16.h>
#include <math.h>

typedef __bf16 bf16x8_t __attribute__((ext_vector_type(8)));
typedef float f32x4 __attribute__((ext_vector_type(4)));
typedef unsigned short ushort8 __attribute__((ext_vector_type(8)));

__device__ inline unsigned short f2bf(float f) {
  unsigned int u = __builtin_bit_cast(unsigned int, f);
  u += 0x7fffu + ((u >> 16) & 1u);
  return (unsigned short)(u >> 16);
}
__device__ inline float b2f(unsigned short s) {
  unsigned int u = ((unsigned int)s) << 16;
  return __builtin_bit_cast(float, u);
}

__device__ __forceinline__ void gll16(const void* g, void* l) {
  __builtin_amdgcn_global_load_lds((const __attribute__((address_space(1))) void*)g,
                                   (__attribute__((address_space(3))) void*)l, 16, 0, 0);
}

// ---------- prepass: fp32 -> bf16 convert ----------
__global__ void cvt_k(const float* __restrict__ X, unsigned short* __restrict__ Xb, int total8) {
  int i = blockIdx.x * blockDim.x + threadIdx.x;
  if (i >= total8) return;
  const float4* p = (const float4*)X + 2 * (size_t)i;
  float4 a = p[0], b = p[1];
  ushort8 v;
  v[0] = f2bf(a.x); v[1] = f2bf(a.y); v[2] = f2bf(a.z); v[3] = f2bf(a.w);
  v[4] = f2bf(b.x); v[5] = f2bf(b.y); v[6] = f2bf(b.z); v[7] = f2bf(b.w);
  ((ushort8*)Xb)[i] = v;
}

// ---------- prepass: transpose + convert: Wt[n][k] = bf16(W[k][n]) ----------
__global__ void twc_k(const float* __restrict__ W, unsigned short* __restrict__ Wt, int K, int N) {
  __shared__ float tile[32][33];
  int k0 = blockIdx.x * 32, n0 = blockIdx.y * 32;
  int tx = threadIdx.x, ty = threadIdx.y;  // 32 x 8
#pragma unroll
  for (int i = 0; i < 32; i += 8) tile[ty + i][tx] = W[(size_t)(k0 + ty + i) * N + n0 + tx];
  __syncthreads();
#pragma unroll
  for (int i = 0; i < 32; i += 8)
    Wt[(size_t)(n0 + ty + i) * K + k0 + tx] = f2bf(tile[tx][ty + i]);
}

// ---------- m97-style GEMM: C[M][N] = A[M][K] @ Bt[N][K]^T ----------
template <bool OUT_BF16>
__global__ __launch_bounds__(256) void gemm_tn(const unsigned short* __restrict__ A,
                                               const unsigned short* __restrict__ Bt,
                                               void* __restrict__ Cv, int M, int N, int K) {
  __shared__ __align__(16) unsigned short As[128 * 32];
  __shared__ __align__(16) unsigned short Bs[128 * 32];
  const int t = threadIdx.x, w = t >> 6, lane = t & 63;
  const int la = lane & 15, lk = lane >> 4;
  const int wr = w >> 1, wc = w & 1;
  const int bm = blockIdx.y * 128, bn = blockIdx.x * 128;
  const int lrow = lane >> 2, lcb = (lane & 3) * 8;

  f32x4 acc[4][4] = {};

  for (int k0 = 0; k0 < K; k0 += 32) {
#pragma unroll
    for (int u = 0; u < 2; ++u) {
      int c = w * 2 + u;
      gll16(A + (size_t)(bm + c * 16 + lrow) * K + k0 + lcb, (char*)As + c * 1024);
      gll16(Bt + (size_t)(bn + c * 16 + lrow) * K + k0 + lcb, (char*)Bs + c * 1024);
    }
    __syncthreads();

    bf16x8_t a[4], b[4];
#pragma unroll
    for (int m = 0; m < 4; ++m)
      a[m] = __builtin_bit_cast(bf16x8_t,
                                *(const ushort8*)(As + (wr * 64 + m * 16 + la) * 32 + lk * 8));
#pragma unroll
    for (int n = 0; n < 4; ++n)
      b[n] = __builtin_bit_cast(bf16x8_t,
                                *(const ushort8*)(Bs + (wc * 64 + n * 16 + la) * 32 + lk * 8));
#pragma unroll
    for (int m = 0; m < 4; ++m)
#pragma unroll
      for (int n = 0; n < 4; ++n)
        acc[m][n] = __builtin_amdgcn_mfma_f32_16x16x32_bf16(a[m], b[n], acc[m][n], 0, 0, 0);
    __syncthreads();
  }

#pragma unroll
  for (int m = 0; m < 4; ++m) {
#pragma unroll
    for (int n = 0; n < 4; ++n) {
#pragma unroll
      for (int r = 0; r < 4; ++r) {
        int row = bm + wr * 64 + m * 16 + lk * 4 + r;
        int col = bn + wc * 64 + n * 16 + la;
        if (OUT_BF16)
          ((unsigned short*)Cv)[(size_t)row * N + col] = f2bf(acc[m][n][r]);
        else
          ((float*)Cv)[(size_t)row * N + col] = acc[m][n][r];
      }
    }
  }
}

// ---------- RoPE ----------
__global__ void rope_k(unsigned short* X, const float* __restrict__ cs,
                       const float* __restrict__ sn, int log2ppr, int rowlen, int total) {
  int idx = blockIdx.x * blockDim.x + threadIdx.x;
  if (idx >= total) return;
  int row = idx >> log2ppr;
  int p = idx & ((1 << log2ppr) - 1);
  int h = p >> 6, i = p & 63;
  int s = row & 2047;
  float c = cs[s * 64 + i], sv = sn[s * 64 + i];
  unsigned short* base = X + (size_t)row * rowlen + h * 128 + 2 * i;
  float e = b2f(base[0]), o = b2f(base[1]);
  base[0] = f2bf(e * c - o * sv);
  base[1] = f2bf(e * sv + o * c);
}

// ---------- V transpose: Vt[(b*4+g)*128 + d][s] = QKV[(b*2048+s)*3072 + 2560 + g*128 + d] ----------
__global__ void transpose_v(const unsigned short* __restrict__ QKV, unsigned short* __restrict__ Vt) {
  __shared__ unsigned short tile[32][33];
  int bg = blockIdx.z;
  int b = bg >> 2, g = bg & 3;
  int s0 = blockIdx.x * 32, d0 = blockIdx.y * 32;
  int tx = threadIdx.x, ty = threadIdx.y;  // 32 x 8
#pragma unroll
  for (int i = 0; i < 32; i += 8)
    tile[ty + i][tx] = QKV[((size_t)(b * 2048 + s0 + ty + i)) * 3072 + 2560 + g * 128 + d0 + tx];
  __syncthreads();
#pragma unroll
  for (int i = 0; i < 32; i += 8)
    Vt[((size_t)(bg * 128 + d0 + ty + i)) * 2048 + s0 + tx] = tile[tx][ty + i];
}

// ---------- MFMA flash attention: 8 waves x 16 q-rows, kv-tile 64, 2-phase gll16 pipeline ----------
// grid (S/128, 16 heads, B), block 512.
__global__ __launch_bounds__(512) void attn_mfma(const unsigned short* __restrict__ QKV,
                                                 const unsigned short* __restrict__ Vt,
                                                 unsigned short* __restrict__ Ob) {
  const int S = 2048;
  __shared__ __align__(16) unsigned short Ks[2][64 * 128];   // linear [krow][d], data pre-swizzled
  __shared__ __align__(16) unsigned short Vs[2][128 * 64];   // linear [d][kv], data pre-swizzled
  __shared__ __align__(16) unsigned short PsA[8 * 16 * 64];  // per-wave P

  const int t = threadIdx.x;
  const int w = t >> 6, lane = t & 63;
  const int la = lane & 15, lk = lane >> 4;
  const int b = blockIdx.z, h = blockIdx.y, g = h >> 2;
  const int qt = gridDim.x - 1 - blockIdx.x;  // heavy tiles first
  const int q0 = qt * 128;
  const int qw = q0 + w * 16;
  const float scale = 0.08838834764831845f;  // 1/sqrt(128)

  // staging geometry: pre-swizzled per-lane GLOBAL source, linear LDS dest (m173 pattern)
  // K: wave w stages groups {2w,2w+1}; group = 4 rows x 16 chunks of 16B
  const int kg0 = w * 2, kg1 = w * 2 + 1;
  const int kr0 = kg0 * 4 + (lane >> 4), kr1 = kg1 * 4 + (lane >> 4);
  const int kp = lane & 15;
  const unsigned short* ksrc0 =
      QKV + (size_t)(b * S + kr0) * 3072 + 2048 + g * 128 + (kp ^ (kr0 & 7)) * 8;
  const unsigned short* ksrc1 =
      QKV + (size_t)(b * S + kr1) * 3072 + 2048 + g * 128 + (kp ^ (kr1 & 7)) * 8;
  // V: group = 8 rows x 8 chunks of 16B
  const int vr0 = kg0 * 8 + (lane >> 3), vr1 = kg1 * 8 + (lane >> 3);
  const int vp = lane & 7;
  const unsigned short* vsrc0 =
      Vt + (size_t)((b * 4 + g) * 128 + vr0) * 2048 + (vp ^ (vr0 & 7)) * 8;
  const unsigned short* vsrc1 =
      Vt + (size_t)((b * 4 + g) * 128 + vr1) * 2048 + (vp ^ (vr1 & 7)) * 8;

  // Q fragments: A-frag row = la, k elems = dt*32 + lk*8 + i
  bf16x8_t qf[4];
#pragma unroll
  for (int dt = 0; dt < 4; ++dt)
    qf[dt] = __builtin_bit_cast(
        bf16x8_t,
        *(const ushort8*)(QKV + (size_t)(b * S + qw + la) * 3072 + h * 128 + dt * 32 + lk * 8));

  f32x4 oa[8];
#pragma unroll
  for (int dt = 0; dt < 8; ++dt) oa[dt] = (f32x4){0.f, 0.f, 0.f, 0.f};
  float mr[4], lr[4];
#pragma unroll
  for (int r = 0; r < 4; ++r) {
    mr[r] = -1e30f;
    lr[r] = 0.f;
  }

  const int n_kt = 2 * qt + 2;
  const int kmask0 = qw & ~63;
  char* pw = (char*)PsA + w * 2048;

  // prologue: stage tile 0 into buf 0
  gll16(ksrc0, (char*)Ks[0] + kg0 * 1024);
  gll16(ksrc1, (char*)Ks[0] + kg1 * 1024);
  gll16(vsrc0, (char*)Vs[0] + kg0 * 1024);
  gll16(vsrc1, (char*)Vs[0] + kg1 * 1024);
  __syncthreads();

  int cur = 0;
  for (int kt = 0; kt < n_kt; ++kt) {
    const int k0 = kt * 64;
    // prefetch next tile into the other buffer (latency hides under compute)
    if (kt + 1 < n_kt) {
      const int kn = k0 + 64;
      gll16(ksrc0 + (size_t)kn * 3072, (char*)Ks[cur ^ 1] + kg0 * 1024);
      gll16(ksrc1 + (size_t)kn * 3072, (char*)Ks[cur ^ 1] + kg1 * 1024);
      gll16(vsrc0 + kn, (char*)Vs[cur ^ 1] + kg0 * 1024);
      gll16(vsrc1 + kn, (char*)Vs[cur ^ 1] + kg1 * 1024);
    }

    if (k0 <= qw + 15) {  // wave not fully masked
      char* Ksb = (char*)Ks[cur];
      char* Vsb = (char*)Vs[cur];

      f32x4 sacc[4];
#pragma unroll
      for (int ktc = 0; ktc < 4; ++ktc) sacc[ktc] = (f32x4){0.f, 0.f, 0.f, 0.f};
      __builtin_amdgcn_s_setprio(1);
#pragma unroll
      for (int ktc = 0; ktc < 4; ++ktc) {
        int row = ktc * 16 + la;
#pragma unroll
        for (int dt = 0; dt < 4; ++dt) {
          bf16x8_t kf = __builtin_bit_cast(
              bf16x8_t, *(const ushort8*)(Ksb + row * 256 + ((((dt << 2) + lk) ^ (row & 7)) << 4)));
          sacc[ktc] = __builtin_amdgcn_mfma_f32_16x16x32_bf16(qf[dt], kf, sacc[ktc], 0, 0, 0);
        }
      }
      __builtin_amdgcn_s_setprio(0);

      const bool domask = (k0 == kmask0);
      float p[4][4], tm[4];
#pragma unroll
      for (int r = 0; r < 4; ++r) tm[r] = -1e30f;
#pragma unroll
      for (int ktc = 0; ktc < 4; ++ktc)
#pragma unroll
        for (int r = 0; r < 4; ++r) {
          float sv = sacc[ktc][r] * scale;
          if (domask && (k0 + ktc * 16 + la > qw + lk * 4 + r)) sv = -1e30f;
          p[ktc][r] = sv;
          tm[r] = fmaxf(tm[r], sv);
        }
#pragma unroll
      for (int r = 0; r < 4; ++r) {
        tm[r] = fmaxf(tm[r], __shfl_xor(tm[r], 1));
        tm[r] = fmaxf(tm[r], __shfl_xor(tm[r], 2));
        tm[r] = fmaxf(tm[r], __shfl_xor(tm[r], 4));
        tm[r] = fmaxf(tm[r], __shfl_xor(tm[r], 8));
      }
      float sc_[4], ts[4];
#pragma unroll
      for (int r = 0; r < 4; ++r) {
        float mn = fmaxf(mr[r], tm[r]);
        sc_[r] = __expf(mr[r] - mn);
        mr[r] = mn;
        ts[r] = 0.f;
      }
#pragma unroll
      for (int ktc = 0; ktc < 4; ++ktc)
#pragma unroll
        for (int r = 0; r < 4; ++r) {
          float e = __expf(p[ktc][r] - mr[r]);
          p[ktc][r] = e;
          ts[r] += e;
        }
#pragma unroll
      for (int r = 0; r < 4; ++r) {
        ts[r] += __shfl_xor(ts[r], 1);
        ts[r] += __shfl_xor(ts[r], 2);
        ts[r] += __shfl_xor(ts[r], 4);
        ts[r] += __shfl_xor(ts[r], 8);
        lr[r] = lr[r] * sc_[r] + ts[r];
      }
#pragma unroll
      for (int dt = 0; dt < 8; ++dt)
#pragma unroll
        for (int r = 0; r < 4; ++r) oa[dt][r] *= sc_[r];
#pragma unroll
      for (int ktc = 0; ktc < 4; ++ktc)
#pragma unroll
        for (int r = 0; r < 4; ++r) {
          int qrow = lk * 4 + r;
          int k = ktc * 16 + la;
          *(unsigned short*)(pw + qrow * 128 + (((k >> 3) ^ (qrow & 7)) << 4) + ((k & 7) << 1)) =
              f2bf(p[ktc][r]);
        }
      asm volatile("s_waitcnt lgkmcnt(0)" ::: "memory");

      bf16x8_t pf[2];
#pragma unroll
      for (int ks = 0; ks < 2; ++ks)
        pf[ks] = __builtin_bit_cast(
            bf16x8_t, *(const ushort8*)(pw + la * 128 + ((((ks << 2) + lk) ^ (la & 7)) << 4)));
      __builtin_amdgcn_s_setprio(1);
#pragma unroll
      for (int dt = 0; dt < 8; ++dt) {
        int d = dt * 16 + la;
#pragma unroll
        for (int ks = 0; ks < 2; ++ks) {
          bf16x8_t vf = __builtin_bit_cast(
              bf16x8_t, *(const ushort8*)(Vsb + d * 128 + ((((ks << 2) + lk) ^ (d & 7)) << 4)));
          oa[dt] = __builtin_amdgcn_mfma_f32_16x16x32_bf16(pf[ks], vf, oa[dt], 0, 0, 0);
        }
      }
      __builtin_amdgcn_s_setprio(0);
    }

    __syncthreads();  // implicit vmcnt(0)+lgkmcnt(0) drain: prefetched tile landed, all reads done
    cur ^= 1;
  }

  float inv[4];
#pragma unroll
  for (int r = 0; r < 4; ++r) inv[r] = 1.f / lr[r];
#pragma unroll
  for (int dt = 0; dt < 8; ++dt)
#pragma unroll
    for (int r = 0; r < 4; ++r)
      Ob[(size_t)(b * S + qw + lk * 4 + r) * 2048 + h * 128 + dt * 16 + la] =
          f2bf(oa[dt][r] * inv[r]);
}

extern "C" void kernel_launch(void* const* d_in, const int* in_sizes, int n_in,
                              void* d_out, int out_size, void* d_ws, size_t ws_size,
                              hipStream_t stream) {
  const float* x = (const float*)d_in[0];
  const float* rc = (const float*)d_in[1];
  const float* rs = (const float*)d_in[2];
  const float* Wq = (const float*)d_in[3];
  const float* Wk = (const float*)d_in[4];
  const float* Wv = (const float*)d_in[5];
  const float* Wo = (const float*)d_in[6];
  float* out = (float*)d_out;

  const int B = 2, S = 2048, DM = 2048;
  const int M = B * S;  // 4096

  // workspace (bf16 elems): xb | QKV | WallT (later WoT + Vt)
  unsigned short* xb = (unsigned short*)d_ws;              // M x 2048      (16 MB)
  unsigned short* QKV = xb + (size_t)M * DM;               // M x 3072      (25.2 MB)
  unsigned short* WallT = QKV + (size_t)M * 3072;          // 3072 x 2048   (12.6 MB)
  unsigned short* WoT = WallT;                             // alias (after QKV proj)
  unsigned short* Vt = WallT + (size_t)2048 * 2048;        // 1024 x 2048 (4 MB, dead Wk/Wv rows)
  unsigned short* Ob = xb;                                 // alias (x dead after proj)

  dim3 blk(256);

  // prepass
  cvt_k<<<(M * DM / 8 + 255) / 256, blk, 0, stream>>>(x, xb, M * DM / 8);
  twc_k<<<dim3(64, 64), dim3(32, 8), 0, stream>>>(Wq, WallT, DM, DM);
  twc_k<<<dim3(64, 16), dim3(32, 8), 0, stream>>>(Wk, WallT + (size_t)2048 * DM, DM, 512);
  twc_k<<<dim3(64, 16), dim3(32, 8), 0, stream>>>(Wv, WallT + (size_t)2560 * DM, DM, 512);

  // fused QKV projection: [M,2048] @ [2048,3072]
  gemm_tn<true><<<dim3(3072 / 128, M / 128), blk, 0, stream>>>(xb, WallT, QKV, M, 3072, DM);

  // Wo transpose (overwrites WallT rows 0..2047)
  twc_k<<<dim3(64, 64), dim3(32, 8), 0, stream>>>(Wo, WoT, DM, DM);

  // RoPE: Q part (1024 pairs/row), K part (256 pairs/row)
  int totq = M * 1024;
  rope_k<<<(totq + 255) / 256, blk, 0, stream>>>(QKV, rc, rs, 10, 3072, totq);
  int totk = M * 256;
  rope_k<<<(totk + 255) / 256, blk, 0, stream>>>(QKV + 2048, rc, rs, 8, 3072, totk);

  transpose_v<<<dim3(S / 32, 4, B * 4), dim3(32, 8), 0, stream>>>(QKV, Vt);

  attn_mfma<<<dim3(S / 128, 16, B), dim3(512), 0, stream>>>(QKV, Vt, Ob);

  gemm_tn<false><<<dim3(DM / 128, M / 128), blk, 0, stream>>>(Ob, WoT, out, M, DM, DM);
}

// Round 8
// 276.134 us; speedup vs baseline: 7.3429x; 1.2006x over previous
//
#include <hip/hip_runtime.h>
#include <hip/hip_bf16.h>
#include <math.h>

typedef __bf16 bf16x8_t __attribute__((ext_vector_type(8)));
typedef float f32x4 __attribute__((ext_vector_type(4)));
typedef unsigned short ushort8 __attribute__((ext_vector_type(8)));

__device__ inline unsigned short f2bf(float f) {
  unsigned int u = __builtin_bit_cast(unsigned int, f);
  u += 0x7fffu + ((u >> 16) & 1u);
  return (unsigned short)(u >> 16);
}
__device__ inline float b2f(unsigned short s) {
  unsigned int u = ((unsigned int)s) << 16;
  return __builtin_bit_cast(float, u);
}
__device__ inline unsigned int pack2bf(float lo, float hi) {
  return (unsigned int)f2bf(lo) | ((unsigned int)f2bf(hi) << 16);
}

__device__ __forceinline__ void gll16(const void* g, void* l) {
  __builtin_amdgcn_global_load_lds((const __attribute__((address_space(1))) void*)g,
                                   (__attribute__((address_space(3))) void*)l, 16, 0, 0);
}

// ---------- prepass: fp32 -> bf16 convert ----------
__global__ void cvt_k(const float* __restrict__ X, unsigned short* __restrict__ Xb, int total8) {
  int i = blockIdx.x * blockDim.x + threadIdx.x;
  if (i >= total8) return;
  const float4* p = (const float4*)X + 2 * (size_t)i;
  float4 a = p[0], b = p[1];
  ushort8 v;
  v[0] = f2bf(a.x); v[1] = f2bf(a.y); v[2] = f2bf(a.z); v[3] = f2bf(a.w);
  v[4] = f2bf(b.x); v[5] = f2bf(b.y); v[6] = f2bf(b.z); v[7] = f2bf(b.w);
  ((ushort8*)Xb)[i] = v;
}

// ---------- prepass: transpose + convert: Wt[n][k] = bf16(W[k][n]) ----------
__global__ void twc_k(const float* __restrict__ W, unsigned short* __restrict__ Wt, int K, int N) {
  __shared__ float tile[32][33];
  int k0 = blockIdx.x * 32, n0 = blockIdx.y * 32;
  int tx = threadIdx.x, ty = threadIdx.y;  // 32 x 8
#pragma unroll
  for (int i = 0; i < 32; i += 8) tile[ty + i][tx] = W[(size_t)(k0 + ty + i) * N + n0 + tx];
  __syncthreads();
#pragma unroll
  for (int i = 0; i < 32; i += 8)
    Wt[(size_t)(n0 + ty + i) * K + k0 + tx] = f2bf(tile[tx][ty + i]);
}

// ---------- m97-style GEMM: C[M][N] = A[M][K] @ Bt[N][K]^T ----------
template <bool OUT_BF16>
__global__ __launch_bounds__(256) void gemm_tn(const unsigned short* __restrict__ A,
                                               const unsigned short* __restrict__ Bt,
                                               void* __restrict__ Cv, int M, int N, int K) {
  __shared__ __align__(16) unsigned short As[128 * 32];
  __shared__ __align__(16) unsigned short Bs[128 * 32];
  const int t = threadIdx.x, w = t >> 6, lane = t & 63;
  const int la = lane & 15, lk = lane >> 4;
  const int wr = w >> 1, wc = w & 1;
  const int bm = blockIdx.y * 128, bn = blockIdx.x * 128;
  const int lrow = lane >> 2, lcb = (lane & 3) * 8;

  f32x4 acc[4][4] = {};

  for (int k0 = 0; k0 < K; k0 += 32) {
#pragma unroll
    for (int u = 0; u < 2; ++u) {
      int c = w * 2 + u;
      gll16(A + (size_t)(bm + c * 16 + lrow) * K + k0 + lcb, (char*)As + c * 1024);
      gll16(Bt + (size_t)(bn + c * 16 + lrow) * K + k0 + lcb, (char*)Bs + c * 1024);
    }
    __syncthreads();

    bf16x8_t a[4], b[4];
#pragma unroll
    for (int m = 0; m < 4; ++m)
      a[m] = __builtin_bit_cast(bf16x8_t,
                                *(const ushort8*)(As + (wr * 64 + m * 16 + la) * 32 + lk * 8));
#pragma unroll
    for (int n = 0; n < 4; ++n)
      b[n] = __builtin_bit_cast(bf16x8_t,
                                *(const ushort8*)(Bs + (wc * 64 + n * 16 + la) * 32 + lk * 8));
#pragma unroll
    for (int m = 0; m < 4; ++m)
#pragma unroll
      for (int n = 0; n < 4; ++n)
        acc[m][n] = __builtin_amdgcn_mfma_f32_16x16x32_bf16(a[m], b[n], acc[m][n], 0, 0, 0);
    __syncthreads();
  }

#pragma unroll
  for (int m = 0; m < 4; ++m) {
#pragma unroll
    for (int n = 0; n < 4; ++n) {
#pragma unroll
      for (int r = 0; r < 4; ++r) {
        int row = bm + wr * 64 + m * 16 + lk * 4 + r;
        int col = bn + wc * 64 + n * 16 + la;
        if (OUT_BF16)
          ((unsigned short*)Cv)[(size_t)row * N + col] = f2bf(acc[m][n][r]);
        else
          ((float*)Cv)[(size_t)row * N + col] = acc[m][n][r];
      }
    }
  }
}

// ---------- RoPE ----------
__global__ void rope_k(unsigned short* X, const float* __restrict__ cs,
                       const float* __restrict__ sn, int log2ppr, int rowlen, int total) {
  int idx = blockIdx.x * blockDim.x + threadIdx.x;
  if (idx >= total) return;
  int row = idx >> log2ppr;
  int p = idx & ((1 << log2ppr) - 1);
  int h = p >> 6, i = p & 63;
  int s = row & 2047;
  float c = cs[s * 64 + i], sv = sn[s * 64 + i];
  unsigned short* base = X + (size_t)row * rowlen + h * 128 + 2 * i;
  float e = b2f(base[0]), o = b2f(base[1]);
  base[0] = f2bf(e * c - o * sv);
  base[1] = f2bf(e * sv + o * c);
}

// ---------- V transpose: Vt[(b*4+g)*128 + d][s] = QKV[(b*2048+s)*3072 + 2560 + g*128 + d] ----------
__global__ void transpose_v(const unsigned short* __restrict__ QKV, unsigned short* __restrict__ Vt) {
  __shared__ unsigned short tile[32][33];
  int bg = blockIdx.z;
  int b = bg >> 2, g = bg & 3;
  int s0 = blockIdx.x * 32, d0 = blockIdx.y * 32;
  int tx = threadIdx.x, ty = threadIdx.y;  // 32 x 8
#pragma unroll
  for (int i = 0; i < 32; i += 8)
    tile[ty + i][tx] = QKV[((size_t)(b * 2048 + s0 + ty + i)) * 3072 + 2560 + g * 128 + d0 + tx];
  __syncthreads();
#pragma unroll
  for (int i = 0; i < 32; i += 8)
    Vt[((size_t)(bg * 128 + d0 + ty + i)) * 2048 + s0 + tx] = tile[tx][ty + i];
}

// ---------- MFMA flash attention: 4 waves x 32 q-rows (2 subtiles), kv-tile 64 ----------
// Swapped QK^T (lane-local softmax rows), packed-P via b64/b128 LDS, 2-phase gll16 pipeline.
// grid (S/128, 16 heads, B), block 256.
__global__ __launch_bounds__(256, 2) void attn_mfma(const unsigned short* __restrict__ QKV,
                                                    const unsigned short* __restrict__ Vt,
                                                    unsigned short* __restrict__ Ob) {
  const int S = 2048;
  __shared__ __align__(16) unsigned short Ks[2][64 * 128];   // linear [krow][d], data pre-swizzled
  __shared__ __align__(16) unsigned short Vs[2][128 * 64];   // linear [d][kv], data pre-swizzled
  __shared__ __align__(16) unsigned short Ps[4 * 32 * 64];   // per-wave packed P [32 q][64 kv]

  const int t = threadIdx.x;
  const int w = t >> 6, lane = t & 63;
  const int la = lane & 15, lk = lane >> 4;
  const int b = blockIdx.z, h = blockIdx.y, g = h >> 2;
  const int qt = gridDim.x - 1 - blockIdx.x;  // heavy tiles first
  const int q0 = qt * 128;
  const int qw = q0 + w * 32;
  const float scale = 0.08838834764831845f;  // 1/sqrt(128)

  // staging: wave w stages K groups 4w..4w+3 (4 rows x 16 chunks) and V groups (8 rows x 8 chunks)
  const unsigned short* ksrc[4];
  const unsigned short* vsrc[4];
#pragma unroll
  for (int u = 0; u < 4; ++u) {
    int kr = 16 * w + 4 * u + (lane >> 4);
    int kp = lane & 15;
    ksrc[u] = QKV + (size_t)(b * S + kr) * 3072 + 2048 + g * 128 + (kp ^ (kr & 7)) * 8;
    int vr = 32 * w + 8 * u + (lane >> 3);
    int vp = lane & 7;
    vsrc[u] = Vt + (size_t)((b * 4 + g) * 128 + vr) * 2048 + (vp ^ (vr & 7)) * 8;
  }

  // Q fragments: qf[qi][dt] at q-row = qw + qi*16 + la, d = dt*32 + lk*8 + i
  bf16x8_t qf[2][4];
#pragma unroll
  for (int qi = 0; qi < 2; ++qi)
#pragma unroll
    for (int dt = 0; dt < 4; ++dt)
      qf[qi][dt] = __builtin_bit_cast(
          bf16x8_t, *(const ushort8*)(QKV + (size_t)(b * S + qw + qi * 16 + la) * 3072 + h * 128 +
                                      dt * 32 + lk * 8));

  f32x4 oa[2][8];
#pragma unroll
  for (int qi = 0; qi < 2; ++qi)
#pragma unroll
    for (int dt = 0; dt < 8; ++dt) oa[qi][dt] = (f32x4){0.f, 0.f, 0.f, 0.f};
  float mr[2] = {-1e30f, -1e30f}, lr[2] = {0.f, 0.f};

  const int n_kt = 2 * qt + 2;
  const int kmask0 = qw & ~63;  // the single partially-masked kv tile for this wave
  char* pw = (char*)Ps + w * 4096;

  // prologue: stage tile 0 into buf 0
#pragma unroll
  for (int u = 0; u < 4; ++u) {
    gll16(ksrc[u], (char*)Ks[0] + (4 * w + u) * 1024);
    gll16(vsrc[u], (char*)Vs[0] + (4 * w + u) * 1024);
  }
  __syncthreads();

  int cur = 0;
  for (int kt = 0; kt < n_kt; ++kt) {
    const int k0 = kt * 64;
    // prefetch next tile into the other buffer
    if (kt + 1 < n_kt) {
      const int kn = k0 + 64;
#pragma unroll
      for (int u = 0; u < 4; ++u) {
        gll16(ksrc[u] + (size_t)kn * 3072, (char*)Ks[cur ^ 1] + (4 * w + u) * 1024);
        gll16(vsrc[u] + kn, (char*)Vs[cur ^ 1] + (4 * w + u) * 1024);
      }
    }

    if (k0 <= qw + 31) {  // wave not fully masked
      char* Ksb = (char*)Ks[cur];
      char* Vsb = (char*)Vs[cur];

      // swapped QK^T: sacc[qi][ktc] = S^T tile: row = kv (lk*4+r within ktc), col = q (la)
      f32x4 sacc[2][4];
#pragma unroll
      for (int qi = 0; qi < 2; ++qi)
#pragma unroll
        for (int ktc = 0; ktc < 4; ++ktc) sacc[qi][ktc] = (f32x4){0.f, 0.f, 0.f, 0.f};
      __builtin_amdgcn_s_setprio(1);
#pragma unroll
      for (int ktc = 0; ktc < 4; ++ktc) {
        int row = ktc * 16 + la;
#pragma unroll
        for (int dt = 0; dt < 4; ++dt) {
          bf16x8_t kf = __builtin_bit_cast(
              bf16x8_t, *(const ushort8*)(Ksb + row * 256 + ((((dt << 2) + lk) ^ (row & 7)) << 4)));
          sacc[0][ktc] = __builtin_amdgcn_mfma_f32_16x16x32_bf16(kf, qf[0][dt], sacc[0][ktc], 0, 0, 0);
          sacc[1][ktc] = __builtin_amdgcn_mfma_f32_16x16x32_bf16(kf, qf[1][dt], sacc[1][ktc], 0, 0, 0);
        }
      }
      __builtin_amdgcn_s_setprio(0);

      const bool domask = (k0 == kmask0);
#pragma unroll
      for (int qi = 0; qi < 2; ++qi) {
        const int q = qw + qi * 16 + la;  // this lane's softmax row
        float p[4][4];
        float tm = -1e30f;
#pragma unroll
        for (int ktc = 0; ktc < 4; ++ktc)
#pragma unroll
          for (int r = 0; r < 4; ++r) {
            float sv = sacc[qi][ktc][r] * scale;
            if (domask && (k0 + ktc * 16 + lk * 4 + r > q)) sv = -1e30f;
            p[ktc][r] = sv;
            tm = fmaxf(tm, sv);
          }
        tm = fmaxf(tm, __shfl_xor(tm, 16));
        tm = fmaxf(tm, __shfl_xor(tm, 32));
        float mn = fmaxf(mr[qi], tm);
        float sc = __expf(mr[qi] - mn);
        mr[qi] = mn;
        float ts = 0.f;
#pragma unroll
        for (int ktc = 0; ktc < 4; ++ktc)
#pragma unroll
          for (int r = 0; r < 4; ++r) {
            float e = __expf(p[ktc][r] - mn);
            p[ktc][r] = e;
            ts += e;
          }
        ts += __shfl_xor(ts, 16);
        ts += __shfl_xor(ts, 32);
        lr[qi] = lr[qi] * sc + ts;
        // broadcast rescale factor to oa's row layout (row q' = lk*4+r lives at lane la=q')
        float scb[4];
#pragma unroll
        for (int r = 0; r < 4; ++r) scb[r] = __shfl(sc, lk * 4 + r);
#pragma unroll
        for (int dt = 0; dt < 8; ++dt)
#pragma unroll
          for (int r = 0; r < 4; ++r) oa[qi][dt][r] *= scb[r];
        // pack P pairs (consecutive kv) and write b64 to swizzled per-wave LDS
        char* pq = pw + (qi * 16 + la) * 128;
#pragma unroll
        for (int ktc = 0; ktc < 4; ++ktc) {
          uint2 gv;
          gv.x = pack2bf(p[ktc][0], p[ktc][1]);
          gv.y = pack2bf(p[ktc][2], p[ktc][3]);
          *(uint2*)(pq + ((32 * ktc + 8 * lk) ^ ((la & 7) << 4))) = gv;
        }
      }
      asm volatile("s_waitcnt lgkmcnt(0)" ::: "memory");

      // P fragments: pf[qi][ks] = P[q = qi*16+la][kv = ks*32 + lk*8 + i]
      bf16x8_t pf[2][2];
#pragma unroll
      for (int qi = 0; qi < 2; ++qi)
#pragma unroll
        for (int ks = 0; ks < 2; ++ks)
          pf[qi][ks] = __builtin_bit_cast(
              bf16x8_t, *(const ushort8*)(pw + (qi * 16 + la) * 128 +
                                          ((64 * ks + 16 * lk) ^ ((la & 7) << 4))));
      __builtin_amdgcn_s_setprio(1);
#pragma unroll
      for (int dt = 0; dt < 8; ++dt) {
        int d = dt * 16 + la;
#pragma unroll
        for (int ks = 0; ks < 2; ++ks) {
          bf16x8_t vf = __builtin_bit_cast(
              bf16x8_t, *(const ushort8*)(Vsb + d * 128 + ((((ks << 2) + lk) ^ (d & 7)) << 4)));
          oa[0][dt] = __builtin_amdgcn_mfma_f32_16x16x32_bf16(pf[0][ks], vf, oa[0][dt], 0, 0, 0);
          oa[1][dt] = __builtin_amdgcn_mfma_f32_16x16x32_bf16(pf[1][ks], vf, oa[1][dt], 0, 0, 0);
        }
      }
      __builtin_amdgcn_s_setprio(0);
    }

    __syncthreads();  // prefetched tile landed; all reads of cur done
    cur ^= 1;
  }

#pragma unroll
  for (int qi = 0; qi < 2; ++qi) {
    float inv = 1.f / lr[qi];
    float invb[4];
#pragma unroll
    for (int r = 0; r < 4; ++r) invb[r] = __shfl(inv, lk * 4 + r);
#pragma unroll
    for (int dt = 0; dt < 8; ++dt)
#pragma unroll
      for (int r = 0; r < 4; ++r)
        Ob[(size_t)(b * S + qw + qi * 16 + lk * 4 + r) * 2048 + h * 128 + dt * 16 + la] =
            f2bf(oa[qi][dt][r] * invb[r]);
  }
}

extern "C" void kernel_launch(void* const* d_in, const int* in_sizes, int n_in,
                              void* d_out, int out_size, void* d_ws, size_t ws_size,
                              hipStream_t stream) {
  const float* x = (const float*)d_in[0];
  const float* rc = (const float*)d_in[1];
  const float* rs = (const float*)d_in[2];
  const float* Wq = (const float*)d_in[3];
  const float* Wk = (const float*)d_in[4];
  const float* Wv = (const float*)d_in[5];
  const float* Wo = (const float*)d_in[6];
  float* out = (float*)d_out;

  const int B = 2, S = 2048, DM = 2048;
  const int M = B * S;  // 4096

  // workspace (bf16 elems): xb | QKV | WallT (later WoT + Vt)
  unsigned short* xb = (unsigned short*)d_ws;              // M x 2048      (16 MB)
  unsigned short* QKV = xb + (size_t)M * DM;               // M x 3072      (25.2 MB)
  unsigned short* WallT = QKV + (size_t)M * 3072;          // 3072 x 2048   (12.6 MB)
  unsigned short* WoT = WallT;                             // alias (after QKV proj)
  unsigned short* Vt = WallT + (size_t)2048 * 2048;        // 1024 x 2048 (4 MB, dead Wk/Wv rows)
  unsigned short* Ob = xb;                                 // alias (x dead after proj)

  dim3 blk(256);

  // prepass
  cvt_k<<<(M * DM / 8 + 255) / 256, blk, 0, stream>>>(x, xb, M * DM / 8);
  twc_k<<<dim3(64, 64), dim3(32, 8), 0, stream>>>(Wq, WallT, DM, DM);
  twc_k<<<dim3(64, 16), dim3(32, 8), 0, stream>>>(Wk, WallT + (size_t)2048 * DM, DM, 512);
  twc_k<<<dim3(64, 16), dim3(32, 8), 0, stream>>>(Wv, WallT + (size_t)2560 * DM, DM, 512);

  // fused QKV projection: [M,2048] @ [2048,3072]
  gemm_tn<true><<<dim3(3072 / 128, M / 128), blk, 0, stream>>>(xb, WallT, QKV, M, 3072, DM);

  // Wo transpose (overwrites WallT rows 0..2047)
  twc_k<<<dim3(64, 64), dim3(32, 8), 0, stream>>>(Wo, WoT, DM, DM);

  // RoPE: Q part (1024 pairs/row), K part (256 pairs/row)
  int totq = M * 1024;
  rope_k<<<(totq + 255) / 256, blk, 0, stream>>>(QKV, rc, rs, 10, 3072, totq);
  int totk = M * 256;
  rope_k<<<(totk + 255) / 256, blk, 0, stream>>>(QKV + 2048, rc, rs, 8, 3072, totk);

  transpose_v<<<dim3(S / 32, 4, B * 4), dim3(32, 8), 0, stream>>>(QKV, Vt);

  attn_mfma<<<dim3(S / 128, 16, B), dim3(256), 0, stream>>>(QKV, Vt, Ob);

  gemm_tn<false><<<dim3(DM / 128, M / 128), blk, 0, stream>>>(Ob, WoT, out, M, DM, DM);
}

// Round 9
// 249.994 us; speedup vs baseline: 8.1107x; 1.1046x over previous
//
#include <hip/hip_runtime.h>
#include <hip/hip_bf16.h>
#include <math.h>

typedef __bf16 bf16x8_t __attribute__((ext_vector_type(8)));
typedef float f32x4 __attribute__((ext_vector_type(4)));
typedef unsigned short ushort8 __attribute__((ext_vector_type(8)));

__device__ inline unsigned short f2bf(float f) {
  unsigned int u = __builtin_bit_cast(unsigned int, f);
  u += 0x7fffu + ((u >> 16) & 1u);
  return (unsigned short)(u >> 16);
}
__device__ inline float b2f(unsigned short s) {
  unsigned int u = ((unsigned int)s) << 16;
  return __builtin_bit_cast(float, u);
}
__device__ inline unsigned int pack2bf(float lo, float hi) {
  return (unsigned int)f2bf(lo) | ((unsigned int)f2bf(hi) << 16);
}

__device__ __forceinline__ void gll16(const void* g, void* l) {
  __builtin_amdgcn_global_load_lds((const __attribute__((address_space(1))) void*)g,
                                   (__attribute__((address_space(3))) void*)l, 16, 0, 0);
}

// ---------- prepass: fp32 -> bf16 convert ----------
__global__ void cvt_k(const float* __restrict__ X, unsigned short* __restrict__ Xb, int total8) {
  int i = blockIdx.x * blockDim.x + threadIdx.x;
  if (i >= total8) return;
  const float4* p = (const float4*)X + 2 * (size_t)i;
  float4 a = p[0], b = p[1];
  ushort8 v;
  v[0] = f2bf(a.x); v[1] = f2bf(a.y); v[2] = f2bf(a.z); v[3] = f2bf(a.w);
  v[4] = f2bf(b.x); v[5] = f2bf(b.y); v[6] = f2bf(b.z); v[7] = f2bf(b.w);
  ((ushort8*)Xb)[i] = v;
}

// ---------- prepass: transpose + convert: Wt[n][k] = bf16(W[k][n]) ----------
__global__ void twc_k(const float* __restrict__ W, unsigned short* __restrict__ Wt, int K, int N) {
  __shared__ float tile[32][33];
  int k0 = blockIdx.x * 32, n0 = blockIdx.y * 32;
  int tx = threadIdx.x, ty = threadIdx.y;  // 32 x 8
#pragma unroll
  for (int i = 0; i < 32; i += 8) tile[ty + i][tx] = W[(size_t)(k0 + ty + i) * N + n0 + tx];
  __syncthreads();
#pragma unroll
  for (int i = 0; i < 32; i += 8)
    Wt[(size_t)(n0 + ty + i) * K + k0 + tx] = f2bf(tile[tx][ty + i]);
}

// ---------- m97-style GEMM: C[M][N] = A[M][K] @ Bt[N][K]^T ----------
template <bool OUT_BF16>
__global__ __launch_bounds__(256) void gemm_tn(const unsigned short* __restrict__ A,
                                               const unsigned short* __restrict__ Bt,
                                               void* __restrict__ Cv, int M, int N, int K) {
  __shared__ __align__(16) unsigned short As[128 * 32];
  __shared__ __align__(16) unsigned short Bs[128 * 32];
  const int t = threadIdx.x, w = t >> 6, lane = t & 63;
  const int la = lane & 15, lk = lane >> 4;
  const int wr = w >> 1, wc = w & 1;
  const int bm = blockIdx.y * 128, bn = blockIdx.x * 128;
  const int lrow = lane >> 2, lcb = (lane & 3) * 8;

  f32x4 acc[4][4] = {};

  for (int k0 = 0; k0 < K; k0 += 32) {
#pragma unroll
    for (int u = 0; u < 2; ++u) {
      int c = w * 2 + u;
      gll16(A + (size_t)(bm + c * 16 + lrow) * K + k0 + lcb, (char*)As + c * 1024);
      gll16(Bt + (size_t)(bn + c * 16 + lrow) * K + k0 + lcb, (char*)Bs + c * 1024);
    }
    __syncthreads();

    bf16x8_t a[4], b[4];
#pragma unroll
    for (int m = 0; m < 4; ++m)
      a[m] = __builtin_bit_cast(bf16x8_t,
                                *(const ushort8*)(As + (wr * 64 + m * 16 + la) * 32 + lk * 8));
#pragma unroll
    for (int n = 0; n < 4; ++n)
      b[n] = __builtin_bit_cast(bf16x8_t,
                                *(const ushort8*)(Bs + (wc * 64 + n * 16 + la) * 32 + lk * 8));
#pragma unroll
    for (int m = 0; m < 4; ++m)
#pragma unroll
      for (int n = 0; n < 4; ++n)
        acc[m][n] = __builtin_amdgcn_mfma_f32_16x16x32_bf16(a[m], b[n], acc[m][n], 0, 0, 0);
    __syncthreads();
  }

#pragma unroll
  for (int m = 0; m < 4; ++m) {
#pragma unroll
    for (int n = 0; n < 4; ++n) {
#pragma unroll
      for (int r = 0; r < 4; ++r) {
        int row = bm + wr * 64 + m * 16 + lk * 4 + r;
        int col = bn + wc * 64 + n * 16 + la;
        if (OUT_BF16)
          ((unsigned short*)Cv)[(size_t)row * N + col] = f2bf(acc[m][n][r]);
        else
          ((float*)Cv)[(size_t)row * N + col] = acc[m][n][r];
      }
    }
  }
}

// ---------- RoPE ----------
__global__ void rope_k(unsigned short* X, const float* __restrict__ cs,
                       const float* __restrict__ sn, int log2ppr, int rowlen, int total) {
  int idx = blockIdx.x * blockDim.x + threadIdx.x;
  if (idx >= total) return;
  int row = idx >> log2ppr;
  int p = idx & ((1 << log2ppr) - 1);
  int h = p >> 6, i = p & 63;
  int s = row & 2047;
  float c = cs[s * 64 + i], sv = sn[s * 64 + i];
  unsigned short* base = X + (size_t)row * rowlen + h * 128 + 2 * i;
  float e = b2f(base[0]), o = b2f(base[1]);
  base[0] = f2bf(e * c - o * sv);
  base[1] = f2bf(e * sv + o * c);
}

// ---------- V transpose: Vt[(b*4+g)*128 + d][s] = QKV[(b*2048+s)*3072 + 2560 + g*128 + d] ----------
__global__ void transpose_v(const unsigned short* __restrict__ QKV, unsigned short* __restrict__ Vt) {
  __shared__ unsigned short tile[32][33];
  int bg = blockIdx.z;
  int b = bg >> 2, g = bg & 3;
  int s0 = blockIdx.x * 32, d0 = blockIdx.y * 32;
  int tx = threadIdx.x, ty = threadIdx.y;  // 32 x 8
#pragma unroll
  for (int i = 0; i < 32; i += 8)
    tile[ty + i][tx] = QKV[((size_t)(b * 2048 + s0 + ty + i)) * 3072 + 2560 + g * 128 + d0 + tx];
  __syncthreads();
#pragma unroll
  for (int i = 0; i < 32; i += 8)
    Vt[((size_t)(bg * 128 + d0 + ty + i)) * 2048 + s0 + tx] = tile[tx][ty + i];
}

// ---------- MFMA flash attention: 4 waves x 32 q-rows (2 subtiles), kv-tile 64 ----------
// Swapped QK^T (lane-local softmax rows), packed-P LDS, 2-phase gll16 pipeline,
// heavy+light qt pairing across the two batches, defer-max (T13).
// grid (S/128, 16 heads, B), block 256.
__global__ __launch_bounds__(256, 2) void attn_mfma(const unsigned short* __restrict__ QKV,
                                                    const unsigned short* __restrict__ Vt,
                                                    unsigned short* __restrict__ Ob) {
  const int S = 2048;
  __shared__ __align__(16) unsigned short Ks[2][64 * 128];   // linear [krow][d], data pre-swizzled
  __shared__ __align__(16) unsigned short Vs[2][128 * 64];   // linear [d][kv], data pre-swizzled
  __shared__ __align__(16) unsigned short Ps[4 * 32 * 64];   // per-wave packed P [32 q][64 kv]

  const int t = threadIdx.x;
  const int w = t >> 6, lane = t & 63;
  const int la = lane & 15, lk = lane >> 4;
  const int b = blockIdx.z, h = blockIdx.y, g = h >> 2;
  // heavy+light pairing: blocks i and i+256 (same CU under round-robin) get qt summing to 15
  const int qt = (b == 0) ? (gridDim.x - 1 - blockIdx.x) : blockIdx.x;
  const int q0 = qt * 128;
  const int qw = q0 + w * 32;
  const float scale = 0.08838834764831845f;  // 1/sqrt(128)

  // staging: wave w stages K groups 4w..4w+3 (4 rows x 16 chunks) and V groups (8 rows x 8 chunks)
  const unsigned short* ksrc[4];
  const unsigned short* vsrc[4];
#pragma unroll
  for (int u = 0; u < 4; ++u) {
    int kr = 16 * w + 4 * u + (lane >> 4);
    int kp = lane & 15;
    ksrc[u] = QKV + (size_t)(b * S + kr) * 3072 + 2048 + g * 128 + (kp ^ (kr & 7)) * 8;
    int vr = 32 * w + 8 * u + (lane >> 3);
    int vp = lane & 7;
    vsrc[u] = Vt + (size_t)((b * 4 + g) * 128 + vr) * 2048 + (vp ^ (vr & 7)) * 8;
  }

  // Q fragments: qf[qi][dt] at q-row = qw + qi*16 + la, d = dt*32 + lk*8 + i
  bf16x8_t qf[2][4];
#pragma unroll
  for (int qi = 0; qi < 2; ++qi)
#pragma unroll
    for (int dt = 0; dt < 4; ++dt)
      qf[qi][dt] = __builtin_bit_cast(
          bf16x8_t, *(const ushort8*)(QKV + (size_t)(b * S + qw + qi * 16 + la) * 3072 + h * 128 +
                                      dt * 32 + lk * 8));

  f32x4 oa[2][8];
#pragma unroll
  for (int qi = 0; qi < 2; ++qi)
#pragma unroll
    for (int dt = 0; dt < 8; ++dt) oa[qi][dt] = (f32x4){0.f, 0.f, 0.f, 0.f};
  float mr[2] = {-1e30f, -1e30f}, lr[2] = {0.f, 0.f};

  const int n_kt = 2 * qt + 2;
  const int kmask0 = qw & ~63;  // the single partially-masked kv tile for this wave
  char* pw = (char*)Ps + w * 4096;

  // prologue: stage tile 0 into buf 0
#pragma unroll
  for (int u = 0; u < 4; ++u) {
    gll16(ksrc[u], (char*)Ks[0] + (4 * w + u) * 1024);
    gll16(vsrc[u], (char*)Vs[0] + (4 * w + u) * 1024);
  }
  __syncthreads();

  int cur = 0;
  for (int kt = 0; kt < n_kt; ++kt) {
    const int k0 = kt * 64;
    // prefetch next tile into the other buffer
    if (kt + 1 < n_kt) {
      const int kn = k0 + 64;
#pragma unroll
      for (int u = 0; u < 4; ++u) {
        gll16(ksrc[u] + (size_t)kn * 3072, (char*)Ks[cur ^ 1] + (4 * w + u) * 1024);
        gll16(vsrc[u] + kn, (char*)Vs[cur ^ 1] + (4 * w + u) * 1024);
      }
    }

    if (k0 <= qw + 31) {  // wave not fully masked
      char* Ksb = (char*)Ks[cur];
      char* Vsb = (char*)Vs[cur];

      // swapped QK^T: sacc[qi][ktc] = S^T tile: row = kv (lk*4+r within ktc), col = q (la)
      f32x4 sacc[2][4];
#pragma unroll
      for (int qi = 0; qi < 2; ++qi)
#pragma unroll
        for (int ktc = 0; ktc < 4; ++ktc) sacc[qi][ktc] = (f32x4){0.f, 0.f, 0.f, 0.f};
      __builtin_amdgcn_s_setprio(1);
#pragma unroll
      for (int ktc = 0; ktc < 4; ++ktc) {
        int row = ktc * 16 + la;
#pragma unroll
        for (int dt = 0; dt < 4; ++dt) {
          bf16x8_t kf = __builtin_bit_cast(
              bf16x8_t, *(const ushort8*)(Ksb + row * 256 + ((((dt << 2) + lk) ^ (row & 7)) << 4)));
          sacc[0][ktc] = __builtin_amdgcn_mfma_f32_16x16x32_bf16(kf, qf[0][dt], sacc[0][ktc], 0, 0, 0);
          sacc[1][ktc] = __builtin_amdgcn_mfma_f32_16x16x32_bf16(kf, qf[1][dt], sacc[1][ktc], 0, 0, 0);
        }
      }
      __builtin_amdgcn_s_setprio(0);

      const bool domask = (k0 == kmask0);
#pragma unroll
      for (int qi = 0; qi < 2; ++qi) {
        const int q = qw + qi * 16 + la;  // this lane's softmax row
        float p[4][4];
        float tm = -1e30f;
#pragma unroll
        for (int ktc = 0; ktc < 4; ++ktc)
#pragma unroll
          for (int r = 0; r < 4; ++r) {
            float sv = sacc[qi][ktc][r] * scale;
            if (domask && (k0 + ktc * 16 + lk * 4 + r > q)) sv = -1e30f;
            p[ktc][r] = sv;
            tm = fmaxf(tm, sv);
          }
        tm = fmaxf(tm, __shfl_xor(tm, 16));
        tm = fmaxf(tm, __shfl_xor(tm, 32));
        // defer-max (T13): skip rescale when tile max growth is small
        float mn;
        if (__all(tm - mr[qi] <= 8.f)) {
          mn = mr[qi];  // keep old max; P bounded by e^8
        } else {
          mn = fmaxf(mr[qi], tm);
          float sc = __expf(mr[qi] - mn);
          mr[qi] = mn;
          lr[qi] *= sc;
          float scb[4];
#pragma unroll
          for (int r = 0; r < 4; ++r) scb[r] = __shfl(sc, lk * 4 + r);
#pragma unroll
          for (int dt = 0; dt < 8; ++dt)
#pragma unroll
            for (int r = 0; r < 4; ++r) oa[qi][dt][r] *= scb[r];
        }
        float ts = 0.f;
#pragma unroll
        for (int ktc = 0; ktc < 4; ++ktc)
#pragma unroll
          for (int r = 0; r < 4; ++r) {
            float e = __expf(p[ktc][r] - mn);
            p[ktc][r] = e;
            ts += e;
          }
        ts += __shfl_xor(ts, 16);
        ts += __shfl_xor(ts, 32);
        lr[qi] += ts;
        // pack P pairs (consecutive kv) and write b64 to swizzled per-wave LDS
        char* pq = pw + (qi * 16 + la) * 128;
#pragma unroll
        for (int ktc = 0; ktc < 4; ++ktc) {
          uint2 gv;
          gv.x = pack2bf(p[ktc][0], p[ktc][1]);
          gv.y = pack2bf(p[ktc][2], p[ktc][3]);
          *(uint2*)(pq + ((32 * ktc + 8 * lk) ^ ((la & 7) << 4))) = gv;
        }
      }
      asm volatile("s_waitcnt lgkmcnt(0)" ::: "memory");

      // P fragments: pf[qi][ks] = P[q = qi*16+la][kv = ks*32 + lk*8 + i]
      bf16x8_t pf[2][2];
#pragma unroll
      for (int qi = 0; qi < 2; ++qi)
#pragma unroll
        for (int ks = 0; ks < 2; ++ks)
          pf[qi][ks] = __builtin_bit_cast(
              bf16x8_t, *(const ushort8*)(pw + (qi * 16 + la) * 128 +
                                          ((64 * ks + 16 * lk) ^ ((la & 7) << 4))));
      __builtin_amdgcn_s_setprio(1);
#pragma unroll
      for (int dt = 0; dt < 8; ++dt) {
        int d = dt * 16 + la;
#pragma unroll
        for (int ks = 0; ks < 2; ++ks) {
          bf16x8_t vf = __builtin_bit_cast(
              bf16x8_t, *(const ushort8*)(Vsb + d * 128 + ((((ks << 2) + lk) ^ (d & 7)) << 4)));
          oa[0][dt] = __builtin_amdgcn_mfma_f32_16x16x32_bf16(pf[0][ks], vf, oa[0][dt], 0, 0, 0);
          oa[1][dt] = __builtin_amdgcn_mfma_f32_16x16x32_bf16(pf[1][ks], vf, oa[1][dt], 0, 0, 0);
        }
      }
      __builtin_amdgcn_s_setprio(0);
    }

    __syncthreads();  // prefetched tile landed; all reads of cur done
    cur ^= 1;
  }

#pragma unroll
  for (int qi = 0; qi < 2; ++qi) {
    float inv = 1.f / lr[qi];
    float invb[4];
#pragma unroll
    for (int r = 0; r < 4; ++r) invb[r] = __shfl(inv, lk * 4 + r);
#pragma unroll
    for (int dt = 0; dt < 8; ++dt)
#pragma unroll
      for (int r = 0; r < 4; ++r)
        Ob[(size_t)(b * S + qw + qi * 16 + lk * 4 + r) * 2048 + h * 128 + dt * 16 + la] =
            f2bf(oa[qi][dt][r] * invb[r]);
  }
}

extern "C" void kernel_launch(void* const* d_in, const int* in_sizes, int n_in,
                              void* d_out, int out_size, void* d_ws, size_t ws_size,
                              hipStream_t stream) {
  const float* x = (const float*)d_in[0];
  const float* rc = (const float*)d_in[1];
  const float* rs = (const float*)d_in[2];
  const float* Wq = (const float*)d_in[3];
  const float* Wk = (const float*)d_in[4];
  const float* Wv = (const float*)d_in[5];
  const float* Wo = (const float*)d_in[6];
  float* out = (float*)d_out;

  const int B = 2, S = 2048, DM = 2048;
  const int M = B * S;  // 4096

  // workspace (bf16 elems): xb | QKV | WallT (later WoT + Vt)
  unsigned short* xb = (unsigned short*)d_ws;              // M x 2048      (16 MB)
  unsigned short* QKV = xb + (size_t)M * DM;               // M x 3072      (25.2 MB)
  unsigned short* WallT = QKV + (size_t)M * 3072;          // 3072 x 2048   (12.6 MB)
  unsigned short* WoT = WallT;                             // alias (after QKV proj)
  unsigned short* Vt = WallT + (size_t)2048 * 2048;        // 1024 x 2048 (4 MB, dead Wk/Wv rows)
  unsigned short* Ob = xb;                                 // alias (x dead after proj)

  dim3 blk(256);

  // prepass
  cvt_k<<<(M * DM / 8 + 255) / 256, blk, 0, stream>>>(x, xb, M * DM / 8);
  twc_k<<<dim3(64, 64), dim3(32, 8), 0, stream>>>(Wq, WallT, DM, DM);
  twc_k<<<dim3(64, 16), dim3(32, 8), 0, stream>>>(Wk, WallT + (size_t)2048 * DM, DM, 512);
  twc_k<<<dim3(64, 16), dim3(32, 8), 0, stream>>>(Wv, WallT + (size_t)2560 * DM, DM, 512);

  // fused QKV projection: [M,2048] @ [2048,3072]
  gemm_tn<true><<<dim3(3072 / 128, M / 128), blk, 0, stream>>>(xb, WallT, QKV, M, 3072, DM);

  // Wo transpose (overwrites WallT rows 0..2047)
  twc_k<<<dim3(64, 64), dim3(32, 8), 0, stream>>>(Wo, WoT, DM, DM);

  // RoPE: Q part (1024 pairs/row), K part (256 pairs/row)
  int totq = M * 1024;
  rope_k<<<(totq + 255) / 256, blk, 0, stream>>>(QKV, rc, rs, 10, 3072, totq);
  int totk = M * 256;
  rope_k<<<(totk + 255) / 256, blk, 0, stream>>>(QKV + 2048, rc, rs, 8, 3072, totk);

  transpose_v<<<dim3(S / 32, 4, B * 4), dim3(32, 8), 0, stream>>>(QKV, Vt);

  attn_mfma<<<dim3(S / 128, 16, B), dim3(256), 0, stream>>>(QKV, Vt, Ob);

  gemm_tn<false><<<dim3(DM / 128, M / 128), blk, 0, stream>>>(Ob, WoT, out, M, DM, DM);
}